// Round 1
// baseline (11629.150 us; speedup 1.0000x reference)
//
#include <hip/hip_runtime.h>
#include <math.h>

#define NN 512
#define BB 32
#define HH 64
#define CC 65      // D_IN + H
#define NC 2080    // CC*BB
#define KRU 260    // CC*4 (features into W)

// ---------------- elementwise / utility ----------------
__global__ void k_zero(float* p, int n) {
  int i = blockIdx.x * 256 + threadIdx.x;
  if (i < n) p[i] = 0.f;
}

__global__ void k_copy(const float* __restrict__ s, float* __restrict__ d, int n) {
  int i = blockIdx.x * 256 + threadIdx.x;
  if (i < n) d[i] = s[i];
}

// T2 = 2*(A@A) - I
__global__ void k_cheb2(const float* __restrict__ AA, float* __restrict__ T2) {
  int i = blockIdx.x * 256 + threadIdx.x;
  if (i < NN * NN) {
    int r = i >> 9, c = i & 511;
    T2[i] = 2.f * AA[i] - (r == c ? 1.f : 0.f);
  }
}

// T3 = 2*(A@T2) - A   (in place on the A@T2 buffer)
__global__ void k_cheb3(float* __restrict__ T3, const float* __restrict__ A) {
  int i = blockIdx.x * 256 + threadIdx.x;
  if (i < NN * NN) T3[i] = 2.f * T3[i] - A[i];
}

// Build X0[n][b*65+d]: d==0 -> x input, d>=1 -> h[b,n,d-1]
// mode 0: x = xbase[(b*12+step)*512+n]; mode 1: x = 0
__global__ void k_build(float* __restrict__ X0, const float* __restrict__ H,
                        const float* __restrict__ xbase, int mode, int step) {
  int e = blockIdx.x * 256 + threadIdx.x;
  if (e >= NN * NC) return;
  int n = e / NC, c = e - n * NC;
  int b = c / CC, d = c - b * CC;
  float v;
  if (d == 0) {
    v = (mode == 1) ? 0.f : xbase[(size_t)(b * 12 + step) * NN + n];
  } else {
    v = H[((size_t)b * NN + n) * HH + (d - 1)];
  }
  X0[e] = v;
}

// ---------------- fp32 tiled GEMM: C[M,N] = A[M,K] @ B[K,N] ----------------
// 128x128 tile, BK=32, 256 threads, 8x8 per thread. K must be multiple of 32.
__global__ __launch_bounds__(256) void gemm_f32(
    const float* __restrict__ A, const float* __restrict__ B, float* __restrict__ C,
    int M, int N, int K) {
  __shared__ float As[128][33];
  __shared__ float Bs[32][132];
  int tid = threadIdx.x;
  int row0 = blockIdx.y * 128, col0 = blockIdx.x * 128;
  int tx = tid & 15, ty = tid >> 4;
  float acc[8][8];
#pragma unroll
  for (int i = 0; i < 8; ++i)
#pragma unroll
    for (int j = 0; j < 8; ++j) acc[i][j] = 0.f;

  for (int k0 = 0; k0 < K; k0 += 32) {
#pragma unroll
    for (int l = 0; l < 16; ++l) {
      int idx = tid + l * 256;             // 0..4095
      int r = idx >> 5, c = idx & 31;      // A tile 128x32
      int gr = row0 + r;
      As[r][c] = (gr < M) ? A[(size_t)gr * K + (k0 + c)] : 0.f;
      int r2 = idx >> 7, c2 = idx & 127;   // B tile 32x128
      int gc = col0 + c2;
      Bs[r2][c2] = (gc < N) ? B[(size_t)(k0 + r2) * N + gc] : 0.f;
    }
    __syncthreads();
#pragma unroll
    for (int kk = 0; kk < 32; ++kk) {
      float a[8], b[8];
#pragma unroll
      for (int i = 0; i < 8; ++i) a[i] = As[ty * 8 + i][kk];
      float4 b0 = *(const float4*)&Bs[kk][tx * 8];
      float4 b1 = *(const float4*)&Bs[kk][tx * 8 + 4];
      b[0] = b0.x; b[1] = b0.y; b[2] = b0.z; b[3] = b0.w;
      b[4] = b1.x; b[5] = b1.y; b[6] = b1.z; b[7] = b1.w;
#pragma unroll
      for (int i = 0; i < 8; ++i)
#pragma unroll
        for (int j = 0; j < 8; ++j) acc[i][j] += a[i] * b[j];
    }
    __syncthreads();
  }
  for (int i = 0; i < 8; ++i) {
    int gr = row0 + ty * 8 + i;
    if (gr >= M) continue;
    for (int j = 0; j < 8; ++j) {
      int gc = col0 + tx * 8 + j;
      if (gc < N) C[(size_t)gr * N + gc] = acc[i][j];
    }
  }
}

// ---------------- W-phase kernels ----------------
// Stage xs[m][n][b*65+d] (m=0 from X0, m>=1 from XS rows (m-1)*512+n) into LDS
// as xls[r][d*4+m], then GEMM against W.

// ru = sigmoid(xk @ Wru + bru); r=cols 0..63, u=cols 64..127.
// Writes rh = r*h into X0 h-columns, u into U.
__global__ __launch_bounds__(256) void k_wru(
    const float* X0, const float* __restrict__ XS,
    const float* __restrict__ W, const float* __restrict__ bias,
    const float* __restrict__ H, float* X0w, float* __restrict__ U) {
  __shared__ float xls[32][264];
  int b = blockIdx.x, n0 = blockIdx.y * 32;
  int tid = threadIdx.x;
  for (int e = tid; e < 4 * NC; e += 256) {
    int m = e / NC;
    int rem = e - m * NC;
    int r = rem / CC, d = rem - r * CC;
    int n = n0 + r;
    float v = (m == 0) ? X0[(size_t)n * NC + b * CC + d]
                       : XS[(size_t)((m - 1) * NN + n) * NC + b * CC + d];
    xls[r][d * 4 + m] = v;
  }
  __syncthreads();
  int jg = tid & 31, rg = tid >> 5;  // 32 j-groups x4 = 128 j; 8 row-groups x4 = 32 rows
  const float4* W4 = (const float4*)W;
  float acc[4][4];
#pragma unroll
  for (int i = 0; i < 4; ++i)
#pragma unroll
    for (int j = 0; j < 4; ++j) acc[i][j] = 0.f;
  for (int k = 0; k < KRU; ++k) {
    float4 wv = W4[k * 32 + jg];
    float x0v = xls[rg * 4 + 0][k];
    float x1v = xls[rg * 4 + 1][k];
    float x2v = xls[rg * 4 + 2][k];
    float x3v = xls[rg * 4 + 3][k];
    acc[0][0] += x0v * wv.x; acc[0][1] += x0v * wv.y; acc[0][2] += x0v * wv.z; acc[0][3] += x0v * wv.w;
    acc[1][0] += x1v * wv.x; acc[1][1] += x1v * wv.y; acc[1][2] += x1v * wv.z; acc[1][3] += x1v * wv.w;
    acc[2][0] += x2v * wv.x; acc[2][1] += x2v * wv.y; acc[2][2] += x2v * wv.z; acc[2][3] += x2v * wv.w;
    acc[3][0] += x3v * wv.x; acc[3][1] += x3v * wv.y; acc[3][2] += x3v * wv.z; acc[3][3] += x3v * wv.w;
  }
#pragma unroll
  for (int i = 0; i < 4; ++i) {
    int n = n0 + rg * 4 + i;
#pragma unroll
    for (int j = 0; j < 4; ++j) {
      int jj = jg * 4 + j;
      float v = acc[i][j] + bias[jj];
      v = 1.f / (1.f + expf(-v));
      if (jj < 64) {
        X0w[(size_t)n * NC + b * CC + 1 + jj] = v * H[((size_t)b * NN + n) * HH + jj];
      } else {
        U[((size_t)b * NN + n) * HH + (jj - 64)] = v;
      }
    }
  }
}

// c = tanh(xk @ Wc + bc); h_new = u*h + (1-u)*c; optionally out = h_new @ Wo + bo
__global__ __launch_bounds__(256) void k_wc(
    const float* __restrict__ X0, const float* __restrict__ XS,
    const float* __restrict__ W, const float* __restrict__ bias,
    const float* __restrict__ U, float* H,
    const float* __restrict__ Wo, const float* __restrict__ bo,
    float* __restrict__ dout, int step) {
  __shared__ float xls[32][264];
  __shared__ float hls[32][68];
  int b = blockIdx.x, n0 = blockIdx.y * 32;
  int tid = threadIdx.x;
  for (int e = tid; e < 4 * NC; e += 256) {
    int m = e / NC;
    int rem = e - m * NC;
    int r = rem / CC, d = rem - r * CC;
    int n = n0 + r;
    float v = (m == 0) ? X0[(size_t)n * NC + b * CC + d]
                       : XS[(size_t)((m - 1) * NN + n) * NC + b * CC + d];
    xls[r][d * 4 + m] = v;
  }
  __syncthreads();
  int jg = tid & 15, rg = tid >> 4;  // 16 j-groups x4 = 64 j; 16 row-groups x2 = 32 rows
  const float4* W4 = (const float4*)W;
  float acc[2][4];
#pragma unroll
  for (int i = 0; i < 2; ++i)
#pragma unroll
    for (int j = 0; j < 4; ++j) acc[i][j] = 0.f;
  for (int k = 0; k < KRU; ++k) {
    float4 wv = W4[k * 16 + jg];
    float x0v = xls[rg * 2 + 0][k];
    float x1v = xls[rg * 2 + 1][k];
    acc[0][0] += x0v * wv.x; acc[0][1] += x0v * wv.y; acc[0][2] += x0v * wv.z; acc[0][3] += x0v * wv.w;
    acc[1][0] += x1v * wv.x; acc[1][1] += x1v * wv.y; acc[1][2] += x1v * wv.z; acc[1][3] += x1v * wv.w;
  }
#pragma unroll
  for (int i = 0; i < 2; ++i) {
    int n = n0 + rg * 2 + i;
#pragma unroll
    for (int j = 0; j < 4; ++j) {
      int jj = jg * 4 + j;
      float cval = tanhf(acc[i][j] + bias[jj]);
      size_t hidx = ((size_t)b * NN + n) * HH + jj;
      float u = U[hidx];
      float hn = u * H[hidx] + (1.f - u) * cval;
      H[hidx] = hn;
      if (dout) hls[rg * 2 + i][jj] = hn;
    }
  }
  if (dout) {
    __syncthreads();
    if (tid < 32) {
      int n = n0 + tid;
      float s = 0.f;
#pragma unroll
      for (int j = 0; j < 64; ++j) s += hls[tid][j] * Wo[j];
      dout[((size_t)b * 12 + step) * NN + n] = s + bo[0];
    }
  }
}

extern "C" void kernel_launch(void* const* d_in, const int* in_sizes, int n_in,
                              void* d_out, int out_size, void* d_ws, size_t ws_size,
                              hipStream_t stream) {
  const float* inputs = (const float*)d_in[0];
  const float* graph  = (const float*)d_in[1];
  const float* eWru = (const float*)d_in[2];
  const float* ebru = (const float*)d_in[3];
  const float* eWc  = (const float*)d_in[4];
  const float* ebc  = (const float*)d_in[5];
  const float* dWru = (const float*)d_in[6];
  const float* dbru = (const float*)d_in[7];
  const float* dWc  = (const float*)d_in[8];
  const float* dbc  = (const float*)d_in[9];
  const float* dWo  = (const float*)d_in[10];
  const float* dbo  = (const float*)d_in[11];
  float* out = (float*)d_out;

  // workspace layout (floats)
  float* Tstack = (float*)d_ws;            // 1536*512   (T1;T2;T3)
  float* TMP    = Tstack + 1536 * 512;     // 512*512
  float* X0     = TMP + 512 * 512;         // 512*2080
  float* XS     = X0 + 512 * 2080;         // 1536*2080
  float* Hbuf   = XS + 1536 * 2080;        // 32*512*64
  float* Ubuf   = Hbuf + 32 * 512 * 64;    // 32*512*64
  size_t need = (size_t)(Ubuf + 32 * 512 * 64 - Tstack) * 4;
  if (ws_size < need) return;  // insufficient scratch; fail loudly via validation

  dim3 blk(256);
  // --- precompute Chebyshev operator stack ---
  k_copy<<<1024, blk, 0, stream>>>(graph, Tstack, 512 * 512);
  gemm_f32<<<dim3(4, 4), blk, 0, stream>>>(graph, graph, TMP, 512, 512, 512);
  k_cheb2<<<1024, blk, 0, stream>>>(TMP, Tstack + 512 * 512);
  gemm_f32<<<dim3(4, 4), blk, 0, stream>>>(graph, Tstack + 512 * 512,
                                           Tstack + 1024 * 512, 512, 512, 512);
  k_cheb3<<<1024, blk, 0, stream>>>(Tstack + 1024 * 512, graph);
  k_zero<<<4096, blk, 0, stream>>>(Hbuf, 32 * 512 * 64);

  dim3 gemmGrid(17, 12);  // ceil(2080/128) x (1536/128)
  dim3 wGrid(32, 16);     // b x n-tiles(32 rows)

  // --- encoder ---
  for (int t = 0; t < 12; ++t) {
    k_build<<<4160, blk, 0, stream>>>(X0, Hbuf, inputs, 0, t);
    gemm_f32<<<gemmGrid, blk, 0, stream>>>(Tstack, X0, XS, 1536, 2080, 512);
    k_wru<<<wGrid, blk, 0, stream>>>(X0, XS, eWru, ebru, Hbuf, X0, Ubuf);
    gemm_f32<<<gemmGrid, blk, 0, stream>>>(Tstack, X0, XS, 1536, 2080, 512);
    k_wc<<<wGrid, blk, 0, stream>>>(X0, XS, eWc, ebc, Ubuf, Hbuf,
                                    nullptr, nullptr, nullptr, 0);
  }
  // --- decoder (autoregressive) ---
  for (int s = 0; s < 12; ++s) {
    if (s == 0) k_build<<<4160, blk, 0, stream>>>(X0, Hbuf, out, 1, 0);
    else        k_build<<<4160, blk, 0, stream>>>(X0, Hbuf, out, 0, s - 1);
    gemm_f32<<<gemmGrid, blk, 0, stream>>>(Tstack, X0, XS, 1536, 2080, 512);
    k_wru<<<wGrid, blk, 0, stream>>>(X0, XS, dWru, dbru, Hbuf, X0, Ubuf);
    gemm_f32<<<gemmGrid, blk, 0, stream>>>(Tstack, X0, XS, 1536, 2080, 512);
    k_wc<<<wGrid, blk, 0, stream>>>(X0, XS, dWc, dbc, Ubuf, Hbuf,
                                    dWo, dbo, out, s);
  }
}

// Round 2
// 3167.713 us; speedup vs baseline: 3.6712x; 3.6712x over previous
//
#include <hip/hip_runtime.h>
#include <hip/hip_bf16.h>
#include <math.h>

#define NN 512
#define BB 32
#define HH 64
#define CC 65      // D_IN + H
#define NC 2080    // CC*BB
#define KRU 260    // CC*4 (features into W)
#define NPAD 2112  // 33*64 padded column count for Xt

typedef __attribute__((ext_vector_type(8))) short bf16x8;
typedef __attribute__((ext_vector_type(4))) float f32x4;

// ---------------- elementwise / utility ----------------
__global__ void k_zero(float* p, int n) {
  int i = blockIdx.x * 256 + threadIdx.x;
  if (i < n) p[i] = 0.f;
}

__global__ void k_copy(const float* __restrict__ s, float* __restrict__ d, int n) {
  int i = blockIdx.x * 256 + threadIdx.x;
  if (i < n) d[i] = s[i];
}

// T2 = 2*(A@A) - I
__global__ void k_cheb2(const float* __restrict__ AA, float* __restrict__ T2) {
  int i = blockIdx.x * 256 + threadIdx.x;
  if (i < NN * NN) {
    int r = i >> 9, c = i & 511;
    T2[i] = 2.f * AA[i] - (r == c ? 1.f : 0.f);
  }
}

// T3 = 2*(A@T2) - A   (in place on the A@T2 buffer)
__global__ void k_cheb3(float* __restrict__ T3, const float* __restrict__ A) {
  int i = blockIdx.x * 256 + threadIdx.x;
  if (i < NN * NN) T3[i] = 2.f * T3[i] - A[i];
}

// split fp32 -> bf16 hi + bf16 lo
__global__ void k_prepT(const float* __restrict__ S, short* __restrict__ hi,
                        short* __restrict__ lo, int n) {
  int i = blockIdx.x * 256 + threadIdx.x;
  if (i >= n) return;
  float x = S[i];
  __hip_bfloat16 h = __float2bfloat16(x);
  float hf = __bfloat162float(h);
  __hip_bfloat16 l = __float2bfloat16(x - hf);
  hi[i] = *(short*)&h;
  lo[i] = *(short*)&l;
}

// Build X0[n][b*65+d]: d==0 -> x input, d>=1 -> h[b,n,d-1]
__global__ void k_build(float* __restrict__ X0, const float* __restrict__ H,
                        const float* __restrict__ xbase, int mode, int step) {
  int e = blockIdx.x * 256 + threadIdx.x;
  if (e >= NN * NC) return;
  int n = e / NC, c = e - n * NC;
  int b = c / CC, d = c - b * CC;
  float v;
  if (d == 0) {
    v = (mode == 1) ? 0.f : xbase[(size_t)(b * 12 + step) * NN + n];
  } else {
    v = H[((size_t)b * NN + n) * HH + (d - 1)];
  }
  X0[e] = v;
}

// transpose + split: X0[512][2080] f32 -> Xt_hi/Xt_lo[NPAD][512] bf16
__global__ __launch_bounds__(256) void k_ts(const float* __restrict__ X0,
                                            short* __restrict__ Xhi,
                                            short* __restrict__ Xlo) {
  __shared__ float t[32][33];
  int c0 = blockIdx.x * 32, k0 = blockIdx.y * 32;
  int tid = threadIdx.x;
  int cc = tid & 31, rr = tid >> 5;
#pragma unroll
  for (int p = 0; p < 4; ++p) {
    int k = k0 + rr + p * 8;
    int c = c0 + cc;
    t[rr + p * 8][cc] = (c < NC) ? X0[(size_t)k * NC + c] : 0.f;
  }
  __syncthreads();
  int kk = tid & 31, c2 = tid >> 5;
#pragma unroll
  for (int p = 0; p < 4; ++p) {
    int c = c0 + c2 + p * 8;
    float x = t[kk][c2 + p * 8];
    __hip_bfloat16 h = __float2bfloat16(x);
    float hf = __bfloat162float(h);
    __hip_bfloat16 l = __float2bfloat16(x - hf);
    size_t o = (size_t)c * 512 + k0 + kk;
    Xhi[o] = *(short*)&h;
    Xlo[o] = *(short*)&l;
  }
}

// ---------------- fp32 tiled GEMM (precompute only) ----------------
__global__ __launch_bounds__(256) void gemm_f32(
    const float* __restrict__ A, const float* __restrict__ B, float* __restrict__ C,
    int M, int N, int K) {
  __shared__ float As[128][33];
  __shared__ float Bs[32][132];
  int tid = threadIdx.x;
  int row0 = blockIdx.y * 128, col0 = blockIdx.x * 128;
  int tx = tid & 15, ty = tid >> 4;
  float acc[8][8];
#pragma unroll
  for (int i = 0; i < 8; ++i)
#pragma unroll
    for (int j = 0; j < 8; ++j) acc[i][j] = 0.f;

  for (int k0 = 0; k0 < K; k0 += 32) {
#pragma unroll
    for (int l = 0; l < 16; ++l) {
      int idx = tid + l * 256;
      int r = idx >> 5, c = idx & 31;
      int gr = row0 + r;
      As[r][c] = (gr < M) ? A[(size_t)gr * K + (k0 + c)] : 0.f;
      int r2 = idx >> 7, c2 = idx & 127;
      int gc = col0 + c2;
      Bs[r2][c2] = (gc < N) ? B[(size_t)(k0 + r2) * N + gc] : 0.f;
    }
    __syncthreads();
#pragma unroll
    for (int kk = 0; kk < 32; ++kk) {
      float a[8], b[8];
#pragma unroll
      for (int i = 0; i < 8; ++i) a[i] = As[ty * 8 + i][kk];
      float4 b0 = *(const float4*)&Bs[kk][tx * 8];
      float4 b1 = *(const float4*)&Bs[kk][tx * 8 + 4];
      b[0] = b0.x; b[1] = b0.y; b[2] = b0.z; b[3] = b0.w;
      b[4] = b1.x; b[5] = b1.y; b[6] = b1.z; b[7] = b1.w;
#pragma unroll
      for (int i = 0; i < 8; ++i)
#pragma unroll
        for (int j = 0; j < 8; ++j) acc[i][j] += a[i] * b[j];
    }
    __syncthreads();
  }
  for (int i = 0; i < 8; ++i) {
    int gr = row0 + ty * 8 + i;
    if (gr >= M) continue;
    for (int j = 0; j < 8; ++j) {
      int gc = col0 + tx * 8 + j;
      if (gc < N) C[(size_t)gr * N + gc] = acc[i][j];
    }
  }
}

// ---------------- MFMA split-bf16 GEMM ----------------
// C[1536, 2080] = sum over 3 segs: Aseg[1536,512](bf16) @ BsegT[c][k](bf16)^T
// BM=128 BN=64 BK=64, 4 waves, 16x16x32 MFMA, global_load_lds + src-side XOR swizzle.
__global__ __launch_bounds__(256) void gemm_mfma_split(
    const short* __restrict__ Thi, const short* __restrict__ Tlo,
    const short* __restrict__ Xhi, const short* __restrict__ Xlo,
    float* __restrict__ C) {
  __shared__ short Abuf[128 * 64];
  __shared__ short Bbuf[64 * 64];
  int tid = threadIdx.x;
  int lane = tid & 63, wid = tid >> 6;
  int m0 = blockIdx.y * 128;
  int c0 = blockIdx.x * 64;
  int wr = wid >> 1, wc = wid & 1;

  f32x4 acc[4][2];
#pragma unroll
  for (int i = 0; i < 4; ++i)
#pragma unroll
    for (int j = 0; j < 2; ++j) acc[i][j] = (f32x4){0.f, 0.f, 0.f, 0.f};

  // staging address precompute (element offsets incl. source-side swizzle)
  int offA[4], offB[2];
#pragma unroll
  for (int q = 0; q < 4; ++q) {
    int i = wid * 4 + q;
    int r = i * 8 + (lane >> 3);
    int j = lane & 7;
    offA[q] = (m0 + r) * 512 + ((j ^ (r & 7)) * 8);
  }
#pragma unroll
  for (int q = 0; q < 2; ++q) {
    int i = wid * 2 + q;
    int r = i * 8 + (lane >> 3);
    int j = lane & 7;
    offB[q] = (c0 + r) * 512 + ((j ^ (r & 7)) * 8);
  }

  const short* Aseg[3] = {Thi, Tlo, Thi};
  const short* Bseg[3] = {Xhi, Xhi, Xlo};

  for (int seg = 0; seg < 3; ++seg) {
    const short* Ab = Aseg[seg];
    const short* Bb = Bseg[seg];
    for (int k0 = 0; k0 < 512; k0 += 64) {
#pragma unroll
      for (int q = 0; q < 4; ++q) {
        __builtin_amdgcn_global_load_lds(
            (const __attribute__((address_space(1))) void*)(Ab + offA[q] + k0),
            (__attribute__((address_space(3))) void*)(Abuf + (wid * 4 + q) * 512),
            16, 0, 0);
      }
#pragma unroll
      for (int q = 0; q < 2; ++q) {
        __builtin_amdgcn_global_load_lds(
            (const __attribute__((address_space(1))) void*)(Bb + offB[q] + k0),
            (__attribute__((address_space(3))) void*)(Bbuf + (wid * 2 + q) * 512),
            16, 0, 0);
      }
      __syncthreads();
#pragma unroll
      for (int ks = 0; ks < 2; ++ks) {
        bf16x8 a[4], b[2];
#pragma unroll
        for (int fm = 0; fm < 4; ++fm) {
          int r = wr * 64 + fm * 16 + (lane & 15);
          int j = (ks * 4 + (lane >> 4)) ^ (r & 7);
          a[fm] = *(const bf16x8*)&Abuf[r * 64 + j * 8];
        }
#pragma unroll
        for (int fn = 0; fn < 2; ++fn) {
          int r = wc * 32 + fn * 16 + (lane & 15);
          int j = (ks * 4 + (lane >> 4)) ^ (r & 7);
          b[fn] = *(const bf16x8*)&Bbuf[r * 64 + j * 8];
        }
#pragma unroll
        for (int fm = 0; fm < 4; ++fm)
#pragma unroll
          for (int fn = 0; fn < 2; ++fn)
            acc[fm][fn] = __builtin_amdgcn_mfma_f32_16x16x32_bf16(
                a[fm], b[fn], acc[fm][fn], 0, 0, 0);
      }
      __syncthreads();
    }
  }

  // epilogue: C/D layout col=lane&15, row=(lane>>4)*4+reg  [m89-verified]
#pragma unroll
  for (int fm = 0; fm < 4; ++fm)
#pragma unroll
    for (int fn = 0; fn < 2; ++fn) {
      int row = m0 + wr * 64 + fm * 16 + (lane >> 4) * 4;
      int col = c0 + wc * 32 + fn * 16 + (lane & 15);
      if (col < NC) {
#pragma unroll
        for (int rr = 0; rr < 4; ++rr)
          C[(size_t)(row + rr) * NC + col] = acc[fm][fn][rr];
      }
    }
}

// ---------------- W-phase kernels (unchanged) ----------------
__global__ __launch_bounds__(256) void k_wru(
    const float* X0, const float* __restrict__ XS,
    const float* __restrict__ W, const float* __restrict__ bias,
    const float* __restrict__ H, float* X0w, float* __restrict__ U) {
  __shared__ float xls[32][264];
  int b = blockIdx.x, n0 = blockIdx.y * 32;
  int tid = threadIdx.x;
  for (int e = tid; e < 4 * NC; e += 256) {
    int m = e / NC;
    int rem = e - m * NC;
    int r = rem / CC, d = rem - r * CC;
    int n = n0 + r;
    float v = (m == 0) ? X0[(size_t)n * NC + b * CC + d]
                       : XS[(size_t)((m - 1) * NN + n) * NC + b * CC + d];
    xls[r][d * 4 + m] = v;
  }
  __syncthreads();
  int jg = tid & 31, rg = tid >> 5;
  const float4* W4 = (const float4*)W;
  float acc[4][4];
#pragma unroll
  for (int i = 0; i < 4; ++i)
#pragma unroll
    for (int j = 0; j < 4; ++j) acc[i][j] = 0.f;
  for (int k = 0; k < KRU; ++k) {
    float4 wv = W4[k * 32 + jg];
    float x0v = xls[rg * 4 + 0][k];
    float x1v = xls[rg * 4 + 1][k];
    float x2v = xls[rg * 4 + 2][k];
    float x3v = xls[rg * 4 + 3][k];
    acc[0][0] += x0v * wv.x; acc[0][1] += x0v * wv.y; acc[0][2] += x0v * wv.z; acc[0][3] += x0v * wv.w;
    acc[1][0] += x1v * wv.x; acc[1][1] += x1v * wv.y; acc[1][2] += x1v * wv.z; acc[1][3] += x1v * wv.w;
    acc[2][0] += x2v * wv.x; acc[2][1] += x2v * wv.y; acc[2][2] += x2v * wv.z; acc[2][3] += x2v * wv.w;
    acc[3][0] += x3v * wv.x; acc[3][1] += x3v * wv.y; acc[3][2] += x3v * wv.z; acc[3][3] += x3v * wv.w;
  }
#pragma unroll
  for (int i = 0; i < 4; ++i) {
    int n = n0 + rg * 4 + i;
#pragma unroll
    for (int j = 0; j < 4; ++j) {
      int jj = jg * 4 + j;
      float v = acc[i][j] + bias[jj];
      v = 1.f / (1.f + expf(-v));
      if (jj < 64) {
        X0w[(size_t)n * NC + b * CC + 1 + jj] = v * H[((size_t)b * NN + n) * HH + jj];
      } else {
        U[((size_t)b * NN + n) * HH + (jj - 64)] = v;
      }
    }
  }
}

__global__ __launch_bounds__(256) void k_wc(
    const float* __restrict__ X0, const float* __restrict__ XS,
    const float* __restrict__ W, const float* __restrict__ bias,
    const float* __restrict__ U, float* H,
    const float* __restrict__ Wo, const float* __restrict__ bo,
    float* __restrict__ dout, int step) {
  __shared__ float xls[32][264];
  __shared__ float hls[32][68];
  int b = blockIdx.x, n0 = blockIdx.y * 32;
  int tid = threadIdx.x;
  for (int e = tid; e < 4 * NC; e += 256) {
    int m = e / NC;
    int rem = e - m * NC;
    int r = rem / CC, d = rem - r * CC;
    int n = n0 + r;
    float v = (m == 0) ? X0[(size_t)n * NC + b * CC + d]
                       : XS[(size_t)((m - 1) * NN + n) * NC + b * CC + d];
    xls[r][d * 4 + m] = v;
  }
  __syncthreads();
  int jg = tid & 15, rg = tid >> 4;
  const float4* W4 = (const float4*)W;
  float acc[2][4];
#pragma unroll
  for (int i = 0; i < 2; ++i)
#pragma unroll
    for (int j = 0; j < 4; ++j) acc[i][j] = 0.f;
  for (int k = 0; k < KRU; ++k) {
    float4 wv = W4[k * 16 + jg];
    float x0v = xls[rg * 2 + 0][k];
    float x1v = xls[rg * 2 + 1][k];
    acc[0][0] += x0v * wv.x; acc[0][1] += x0v * wv.y; acc[0][2] += x0v * wv.z; acc[0][3] += x0v * wv.w;
    acc[1][0] += x1v * wv.x; acc[1][1] += x1v * wv.y; acc[1][2] += x1v * wv.z; acc[1][3] += x1v * wv.w;
  }
#pragma unroll
  for (int i = 0; i < 2; ++i) {
    int n = n0 + rg * 2 + i;
#pragma unroll
    for (int j = 0; j < 4; ++j) {
      int jj = jg * 4 + j;
      float cval = tanhf(acc[i][j] + bias[jj]);
      size_t hidx = ((size_t)b * NN + n) * HH + jj;
      float u = U[hidx];
      float hn = u * H[hidx] + (1.f - u) * cval;
      H[hidx] = hn;
      if (dout) hls[rg * 2 + i][jj] = hn;
    }
  }
  if (dout) {
    __syncthreads();
    if (tid < 32) {
      int n = n0 + tid;
      float s = 0.f;
#pragma unroll
      for (int j = 0; j < 64; ++j) s += hls[tid][j] * Wo[j];
      dout[((size_t)b * 12 + step) * NN + n] = s + bo[0];
    }
  }
}

extern "C" void kernel_launch(void* const* d_in, const int* in_sizes, int n_in,
                              void* d_out, int out_size, void* d_ws, size_t ws_size,
                              hipStream_t stream) {
  const float* inputs = (const float*)d_in[0];
  const float* graph  = (const float*)d_in[1];
  const float* eWru = (const float*)d_in[2];
  const float* ebru = (const float*)d_in[3];
  const float* eWc  = (const float*)d_in[4];
  const float* ebc  = (const float*)d_in[5];
  const float* dWru = (const float*)d_in[6];
  const float* dbru = (const float*)d_in[7];
  const float* dWc  = (const float*)d_in[8];
  const float* dbc  = (const float*)d_in[9];
  const float* dWo  = (const float*)d_in[10];
  const float* dbo  = (const float*)d_in[11];
  float* out = (float*)d_out;

  // workspace carve (bytes)
  char* w = (char*)d_ws;
  float* Tstack = (float*)w;                 w += (size_t)1536 * 512 * 4;
  float* TMP    = (float*)w;                 w += (size_t)512 * 512 * 4;
  float* X0     = (float*)w;                 w += (size_t)512 * NC * 4;
  float* XS     = (float*)w;                 w += (size_t)1536 * NC * 4;
  float* Hbuf   = (float*)w;                 w += (size_t)32 * 512 * 64 * 4;
  float* Ubuf   = (float*)w;                 w += (size_t)32 * 512 * 64 * 4;
  short* Thi    = (short*)w;                 w += (size_t)1536 * 512 * 2;
  short* Tlo    = (short*)w;                 w += (size_t)1536 * 512 * 2;
  short* Xthi   = (short*)w;                 w += (size_t)NPAD * 512 * 2;
  short* Xtlo   = (short*)w;                 w += (size_t)NPAD * 512 * 2;
  size_t need = (size_t)(w - (char*)d_ws);
  if (ws_size < need) return;

  dim3 blk(256);
  // --- precompute Chebyshev operator stack (fp32, exact as before) ---
  k_copy<<<1024, blk, 0, stream>>>(graph, Tstack, 512 * 512);
  gemm_f32<<<dim3(4, 4), blk, 0, stream>>>(graph, graph, TMP, 512, 512, 512);
  k_cheb2<<<1024, blk, 0, stream>>>(TMP, Tstack + 512 * 512);
  gemm_f32<<<dim3(4, 4), blk, 0, stream>>>(graph, Tstack + 512 * 512,
                                           Tstack + 1024 * 512, 512, 512, 512);
  k_cheb3<<<1024, blk, 0, stream>>>(Tstack + 1024 * 512, graph);
  k_prepT<<<3072, blk, 0, stream>>>(Tstack, Thi, Tlo, 1536 * 512);
  k_zero<<<4096, blk, 0, stream>>>(Hbuf, 32 * 512 * 64);

  dim3 tsGrid(66, 16);    // c-tiles x k-tiles
  dim3 gemmGrid(33, 12);  // c-tiles(64) x m-tiles(128)
  dim3 wGrid(32, 16);

  // --- encoder ---
  for (int t = 0; t < 12; ++t) {
    k_build<<<4160, blk, 0, stream>>>(X0, Hbuf, inputs, 0, t);
    k_ts<<<tsGrid, blk, 0, stream>>>(X0, Xthi, Xtlo);
    gemm_mfma_split<<<gemmGrid, blk, 0, stream>>>(Thi, Tlo, Xthi, Xtlo, XS);
    k_wru<<<wGrid, blk, 0, stream>>>(X0, XS, eWru, ebru, Hbuf, X0, Ubuf);
    k_ts<<<tsGrid, blk, 0, stream>>>(X0, Xthi, Xtlo);
    gemm_mfma_split<<<gemmGrid, blk, 0, stream>>>(Thi, Tlo, Xthi, Xtlo, XS);
    k_wc<<<wGrid, blk, 0, stream>>>(X0, XS, eWc, ebc, Ubuf, Hbuf,
                                    nullptr, nullptr, nullptr, 0);
  }
  // --- decoder (autoregressive) ---
  for (int s = 0; s < 12; ++s) {
    if (s == 0) k_build<<<4160, blk, 0, stream>>>(X0, Hbuf, out, 1, 0);
    else        k_build<<<4160, blk, 0, stream>>>(X0, Hbuf, out, 0, s - 1);
    k_ts<<<tsGrid, blk, 0, stream>>>(X0, Xthi, Xtlo);
    gemm_mfma_split<<<gemmGrid, blk, 0, stream>>>(Thi, Tlo, Xthi, Xtlo, XS);
    k_wru<<<wGrid, blk, 0, stream>>>(X0, XS, dWru, dbru, Hbuf, X0, Ubuf);
    k_ts<<<tsGrid, blk, 0, stream>>>(X0, Xthi, Xtlo);
    gemm_mfma_split<<<gemmGrid, blk, 0, stream>>>(Thi, Tlo, Xthi, Xtlo, XS);
    k_wc<<<wGrid, blk, 0, stream>>>(X0, XS, dWc, dbc, Ubuf, Hbuf,
                                    dWo, dbo, out, s);
  }
}

// Round 3
// 2877.866 us; speedup vs baseline: 4.0409x; 1.1007x over previous
//
#include <hip/hip_runtime.h>
#include <hip/hip_bf16.h>
#include <math.h>

#define NN 512
#define BB 32
#define HH 64
#define CC 65      // D_IN + H
#define NC 2080    // CC*BB
#define KRU 260    // CC*4 (features into W)
#define NPAD 2112  // 33*64 padded row count for Xt

typedef __attribute__((ext_vector_type(8))) short bf16x8;
typedef __attribute__((ext_vector_type(4))) float f32x4;

__device__ __forceinline__ float b2f(short s) {
  return __bfloat162float(*(__hip_bfloat16*)&s);
}
__device__ __forceinline__ void f2b2(float x, short& hi, short& lo) {
  __hip_bfloat16 h = __float2bfloat16(x);
  float hf = __bfloat162float(h);
  __hip_bfloat16 l = __float2bfloat16(x - hf);
  hi = *(short*)&h; lo = *(short*)&l;
}

// ---------------- utility ----------------
__global__ void k_zero(float* p, int n) {
  int i = blockIdx.x * 256 + threadIdx.x;
  if (i < n) p[i] = 0.f;
}

// split fp32 -> bf16 hi + lo (used for graph rows of T-stack)
__global__ void k_prepT(const float* __restrict__ S, short* __restrict__ hi,
                        short* __restrict__ lo, int n) {
  int i = blockIdx.x * 256 + threadIdx.x;
  if (i >= n) return;
  short h, l; f2b2(S[i], h, l);
  hi[i] = h; lo[i] = l;
}

// T2 = 2*AA - I ; writes f32 back into AA and split into hi/lo
__global__ void k_cheb2b(float* __restrict__ AA, short* __restrict__ hi,
                         short* __restrict__ lo) {
  int i = blockIdx.x * 256 + threadIdx.x;
  if (i >= NN * NN) return;
  int r = i >> 9, c = i & 511;
  float v = 2.f * AA[i] - (r == c ? 1.f : 0.f);
  AA[i] = v;
  short h, l; f2b2(v, h, l);
  hi[i] = h; lo[i] = l;
}

// T3 = 2*(A@T2) - A ; split only (no f32 needed downstream)
__global__ void k_cheb3b(const float* __restrict__ AT2, const float* __restrict__ A,
                         short* __restrict__ hi, short* __restrict__ lo) {
  int i = blockIdx.x * 256 + threadIdx.x;
  if (i >= NN * NN) return;
  float v = 2.f * AT2[i] - A[i];
  short h, l; f2b2(v, h, l);
  hi[i] = h; lo[i] = l;
}

// transpose + split a 512x512 f32 matrix -> [c][r] bf16 hi/lo
__global__ __launch_bounds__(256) void t512(const float* __restrict__ in,
                                            short* __restrict__ ohi,
                                            short* __restrict__ olo) {
  __shared__ float t[32][33];
  int c0 = blockIdx.x * 32, r0 = blockIdx.y * 32;
  int tid = threadIdx.x;
  int cc = tid & 31, rr = tid >> 5;
#pragma unroll
  for (int p = 0; p < 4; ++p)
    t[rr + p * 8][cc] = in[(size_t)(r0 + rr + p * 8) * 512 + c0 + cc];
  __syncthreads();
#pragma unroll
  for (int p = 0; p < 4; ++p) {
    int c = rr + p * 8, r = cc;
    short h, l; f2b2(t[r][c], h, l);
    size_t o = (size_t)(c0 + c) * 512 + r0 + r;
    ohi[o] = h; olo[o] = l;
  }
}

// Build Xt[c][n] (hi/lo) for concat [x, h]; also write x column into X2.
__global__ __launch_bounds__(256) void k_buildt(
    short* __restrict__ Xthi, short* __restrict__ Xtlo,
    short* __restrict__ X2hi, short* __restrict__ X2lo,
    const float* __restrict__ H, const float* __restrict__ xbase,
    int mode, int step) {
  __shared__ float t[64][65];
  int n0 = blockIdx.x * 64, b = blockIdx.y;
  int tid = threadIdx.x;
#pragma unroll
  for (int l = 0; l < 16; ++l) {
    int idx = tid + l * 256;
    int r = idx >> 6, j = idx & 63;
    t[r][j] = H[((size_t)b * 512 + n0 + r) * 64 + j];
  }
  __syncthreads();
#pragma unroll
  for (int l = 0; l < 16; ++l) {
    int idx = tid + l * 256;
    int j = idx >> 6, nn = idx & 63;
    short h, l2; f2b2(t[nn][j], h, l2);
    size_t o = (size_t)(b * CC + 1 + j) * 512 + n0 + nn;
    Xthi[o] = h; Xtlo[o] = l2;
  }
  if (tid < 64) {
    int n = n0 + tid;
    float x = (mode == 1) ? 0.f : xbase[((size_t)b * 12 + step) * 512 + n];
    short h, l2; f2b2(x, h, l2);
    size_t o = (size_t)(b * CC) * 512 + n;
    Xthi[o] = h; Xtlo[o] = l2;
    X2hi[o] = h; X2lo[o] = l2;
  }
}

// ---------------- MFMA split-bf16 GEMM (generic) ----------------
// C[M, ncols] = sum over 3 segs of A(hi/lo)[M,512] @ B(hi/lo)[c][k]^T
// BM=128 BN=64 BK=64, 4 waves, 16x16x32 MFMA, global_load_lds + src-side XOR swizzle.
__global__ __launch_bounds__(256) void gemm_mfma_split(
    const short* __restrict__ Ahi, const short* __restrict__ Alo,
    const short* __restrict__ Bhi, const short* __restrict__ Blo,
    float* __restrict__ C, int ncols, int ldc) {
  __shared__ short Abuf[128 * 64];
  __shared__ short Bbuf[64 * 64];
  int tid = threadIdx.x;
  int lane = tid & 63, wid = tid >> 6;
  int m0 = blockIdx.y * 128;
  int c0 = blockIdx.x * 64;
  int wr = wid >> 1, wc = wid & 1;

  f32x4 acc[4][2];
#pragma unroll
  for (int i = 0; i < 4; ++i)
#pragma unroll
    for (int j = 0; j < 2; ++j) acc[i][j] = (f32x4){0.f, 0.f, 0.f, 0.f};

  int offA[4], offB[2];
#pragma unroll
  for (int q = 0; q < 4; ++q) {
    int i = wid * 4 + q;
    int r = i * 8 + (lane >> 3);
    int j = lane & 7;
    offA[q] = (m0 + r) * 512 + ((j ^ (r & 7)) * 8);
  }
#pragma unroll
  for (int q = 0; q < 2; ++q) {
    int i = wid * 2 + q;
    int r = i * 8 + (lane >> 3);
    int j = lane & 7;
    offB[q] = (c0 + r) * 512 + ((j ^ (r & 7)) * 8);
  }

  const short* Aseg[3] = {Ahi, Alo, Ahi};
  const short* Bseg[3] = {Bhi, Bhi, Blo};

  for (int seg = 0; seg < 3; ++seg) {
    const short* Ab = Aseg[seg];
    const short* Bb = Bseg[seg];
    for (int k0 = 0; k0 < 512; k0 += 64) {
#pragma unroll
      for (int q = 0; q < 4; ++q) {
        __builtin_amdgcn_global_load_lds(
            (const __attribute__((address_space(1))) void*)(Ab + offA[q] + k0),
            (__attribute__((address_space(3))) void*)(Abuf + (wid * 4 + q) * 512),
            16, 0, 0);
      }
#pragma unroll
      for (int q = 0; q < 2; ++q) {
        __builtin_amdgcn_global_load_lds(
            (const __attribute__((address_space(1))) void*)(Bb + offB[q] + k0),
            (__attribute__((address_space(3))) void*)(Bbuf + (wid * 2 + q) * 512),
            16, 0, 0);
      }
      __syncthreads();
#pragma unroll
      for (int ks = 0; ks < 2; ++ks) {
        bf16x8 a[4], b[2];
#pragma unroll
        for (int fm = 0; fm < 4; ++fm) {
          int r = wr * 64 + fm * 16 + (lane & 15);
          int j = (ks * 4 + (lane >> 4)) ^ (r & 7);
          a[fm] = *(const bf16x8*)&Abuf[r * 64 + j * 8];
        }
#pragma unroll
        for (int fn = 0; fn < 2; ++fn) {
          int r = wc * 32 + fn * 16 + (lane & 15);
          int j = (ks * 4 + (lane >> 4)) ^ (r & 7);
          b[fn] = *(const bf16x8*)&Bbuf[r * 64 + j * 8];
        }
#pragma unroll
        for (int fm = 0; fm < 4; ++fm)
#pragma unroll
          for (int fn = 0; fn < 2; ++fn)
            acc[fm][fn] = __builtin_amdgcn_mfma_f32_16x16x32_bf16(
                a[fm], b[fn], acc[fm][fn], 0, 0, 0);
      }
      __syncthreads();
    }
  }

#pragma unroll
  for (int fm = 0; fm < 4; ++fm)
#pragma unroll
    for (int fn = 0; fn < 2; ++fn) {
      int row = m0 + wr * 64 + fm * 16 + (lane >> 4) * 4;
      int col = c0 + wc * 32 + fn * 16 + (lane & 15);
      if (col < ncols) {
#pragma unroll
        for (int rr = 0; rr < 4; ++rr)
          C[(size_t)(row + rr) * ldc + col] = acc[fm][fn][rr];
      }
    }
}

// ---------------- W-phase kernels ----------------
// z=0: r-half -> write r*h (split) into X2. z=1: u-half -> write U.
__global__ __launch_bounds__(256) void k_wru(
    const short* __restrict__ Xthi, const short* __restrict__ Xtlo,
    const float* __restrict__ XS,
    const float* __restrict__ W, const float* __restrict__ bias,
    const float* __restrict__ H,
    short* __restrict__ X2hi, short* __restrict__ X2lo,
    float* __restrict__ U) {
  __shared__ float xls[32][264];
  int b = blockIdx.x, n0 = blockIdx.y * 32, z = blockIdx.z;
  int tid = threadIdx.x;
  for (int e = tid; e < 32 * CC; e += 256) {
    int d = e >> 5, r = e & 31;
    size_t o = (size_t)(b * CC + d) * 512 + n0 + r;
    xls[r][d * 4] = b2f(Xthi[o]) + b2f(Xtlo[o]);
  }
  for (int e = tid; e < 3 * NC; e += 256) {
    int m = e / NC; int rem = e - m * NC;
    int r = rem / CC, d = rem - r * CC;
    xls[r][d * 4 + m + 1] = XS[(size_t)(m * 512 + n0 + r) * NC + b * CC + d];
  }
  __syncthreads();
  int jg = tid & 15, rg = tid >> 4;
  const float4* W4 = (const float4*)W;  // 32 float4 per k-row
  float acc[2][4];
#pragma unroll
  for (int i = 0; i < 2; ++i)
#pragma unroll
    for (int j = 0; j < 4; ++j) acc[i][j] = 0.f;
#pragma unroll 4
  for (int k = 0; k < KRU; ++k) {
    float4 wv = W4[k * 32 + z * 16 + jg];
    float x0 = xls[rg * 2 + 0][k];
    float x1 = xls[rg * 2 + 1][k];
    acc[0][0] += x0 * wv.x; acc[0][1] += x0 * wv.y; acc[0][2] += x0 * wv.z; acc[0][3] += x0 * wv.w;
    acc[1][0] += x1 * wv.x; acc[1][1] += x1 * wv.y; acc[1][2] += x1 * wv.z; acc[1][3] += x1 * wv.w;
  }
  if (z == 0) {
    __syncthreads();
    float* rls = &xls[0][0];  // reuse as [32][64]
#pragma unroll
    for (int i = 0; i < 2; ++i) {
      int n = n0 + rg * 2 + i;
      const float4 h4 = *(const float4*)&H[((size_t)b * 512 + n) * 64 + jg * 4];
      const float hv[4] = {h4.x, h4.y, h4.z, h4.w};
#pragma unroll
      for (int j = 0; j < 4; ++j) {
        int jj = jg * 4 + j;
        float v = 1.f / (1.f + expf(-(acc[i][j] + bias[jj])));
        rls[(rg * 2 + i) * 64 + jj] = v * hv[j];
      }
    }
    __syncthreads();
    for (int e = tid; e < 64 * 32; e += 256) {
      int j = e >> 5, nn = e & 31;
      short h, l; f2b2(rls[nn * 64 + j], h, l);
      size_t o = (size_t)(b * CC + 1 + j) * 512 + n0 + nn;
      X2hi[o] = h; X2lo[o] = l;
    }
  } else {
#pragma unroll
    for (int i = 0; i < 2; ++i) {
      int n = n0 + rg * 2 + i;
      float4 uv;
      uv.x = 1.f / (1.f + expf(-(acc[i][0] + bias[64 + jg * 4 + 0])));
      uv.y = 1.f / (1.f + expf(-(acc[i][1] + bias[64 + jg * 4 + 1])));
      uv.z = 1.f / (1.f + expf(-(acc[i][2] + bias[64 + jg * 4 + 2])));
      uv.w = 1.f / (1.f + expf(-(acc[i][3] + bias[64 + jg * 4 + 3])));
      *(float4*)&U[((size_t)b * 512 + n) * 64 + jg * 4] = uv;
    }
  }
}

// c = tanh(xk @ Wc + bc); h = u*h + (1-u)*c; optional out = h @ Wo + bo
__global__ __launch_bounds__(256) void k_wc(
    const short* __restrict__ X2hi, const short* __restrict__ X2lo,
    const float* __restrict__ XS,
    const float* __restrict__ W, const float* __restrict__ bias,
    const float* __restrict__ U, float* __restrict__ H,
    const float* __restrict__ Wo, const float* __restrict__ bo,
    float* __restrict__ dout, int step) {
  __shared__ float xls[32][264];
  int b = blockIdx.x, n0 = blockIdx.y * 32;
  int tid = threadIdx.x;
  for (int e = tid; e < 32 * CC; e += 256) {
    int d = e >> 5, r = e & 31;
    size_t o = (size_t)(b * CC + d) * 512 + n0 + r;
    xls[r][d * 4] = b2f(X2hi[o]) + b2f(X2lo[o]);
  }
  for (int e = tid; e < 3 * NC; e += 256) {
    int m = e / NC; int rem = e - m * NC;
    int r = rem / CC, d = rem - r * CC;
    xls[r][d * 4 + m + 1] = XS[(size_t)(m * 512 + n0 + r) * NC + b * CC + d];
  }
  __syncthreads();
  int jg = tid & 15, rg = tid >> 4;
  const float4* W4 = (const float4*)W;  // 16 float4 per k-row
  float acc[2][4];
#pragma unroll
  for (int i = 0; i < 2; ++i)
#pragma unroll
    for (int j = 0; j < 4; ++j) acc[i][j] = 0.f;
#pragma unroll 4
  for (int k = 0; k < KRU; ++k) {
    float4 wv = W4[k * 16 + jg];
    float x0 = xls[rg * 2 + 0][k];
    float x1 = xls[rg * 2 + 1][k];
    acc[0][0] += x0 * wv.x; acc[0][1] += x0 * wv.y; acc[0][2] += x0 * wv.z; acc[0][3] += x0 * wv.w;
    acc[1][0] += x1 * wv.x; acc[1][1] += x1 * wv.y; acc[1][2] += x1 * wv.z; acc[1][3] += x1 * wv.w;
  }
  __syncthreads();
  float* hl = &xls[0][0];  // reuse as [32][66]
#pragma unroll
  for (int i = 0; i < 2; ++i) {
    int n = n0 + rg * 2 + i;
    size_t hb = ((size_t)b * 512 + n) * 64 + jg * 4;
    float4 h4 = *(const float4*)&H[hb];
    float4 u4 = *(const float4*)&U[hb];
    float4 hn;
    hn.x = u4.x * h4.x + (1.f - u4.x) * tanhf(acc[i][0] + bias[jg * 4 + 0]);
    hn.y = u4.y * h4.y + (1.f - u4.y) * tanhf(acc[i][1] + bias[jg * 4 + 1]);
    hn.z = u4.z * h4.z + (1.f - u4.z) * tanhf(acc[i][2] + bias[jg * 4 + 2]);
    hn.w = u4.w * h4.w + (1.f - u4.w) * tanhf(acc[i][3] + bias[jg * 4 + 3]);
    *(float4*)&H[hb] = hn;
    if (dout) {
      hl[(rg * 2 + i) * 66 + jg * 4 + 0] = hn.x;
      hl[(rg * 2 + i) * 66 + jg * 4 + 1] = hn.y;
      hl[(rg * 2 + i) * 66 + jg * 4 + 2] = hn.z;
      hl[(rg * 2 + i) * 66 + jg * 4 + 3] = hn.w;
    }
  }
  if (dout) {
    __syncthreads();
    if (tid < 32) {
      int n = n0 + tid;
      float s = 0.f;
#pragma unroll
      for (int j = 0; j < 64; ++j) s += hl[tid * 66 + j] * Wo[j];
      dout[((size_t)b * 12 + step) * 512 + n] = s + bo[0];
    }
  }
}

extern "C" void kernel_launch(void* const* d_in, const int* in_sizes, int n_in,
                              void* d_out, int out_size, void* d_ws, size_t ws_size,
                              hipStream_t stream) {
  const float* inputs = (const float*)d_in[0];
  const float* graph  = (const float*)d_in[1];
  const float* eWru = (const float*)d_in[2];
  const float* ebru = (const float*)d_in[3];
  const float* eWc  = (const float*)d_in[4];
  const float* ebc  = (const float*)d_in[5];
  const float* dWru = (const float*)d_in[6];
  const float* dbru = (const float*)d_in[7];
  const float* dWc  = (const float*)d_in[8];
  const float* dbc  = (const float*)d_in[9];
  const float* dWo  = (const float*)d_in[10];
  const float* dbo  = (const float*)d_in[11];
  float* out = (float*)d_out;

  char* w = (char*)d_ws;
  float* TMP  = (float*)w;  w += (size_t)512 * 512 * 4;
  float* XS   = (float*)w;  w += (size_t)1536 * NC * 4;
  float* Hbuf = (float*)w;  w += (size_t)32 * 512 * 64 * 4;
  float* Ubuf = (float*)w;  w += (size_t)32 * 512 * 64 * 4;
  short* Thi  = (short*)w;  w += (size_t)1536 * 512 * 2;
  short* Tlo  = (short*)w;  w += (size_t)1536 * 512 * 2;
  short* Xthi = (short*)w;  w += (size_t)NPAD * 512 * 2;
  short* Xtlo = (short*)w;  w += (size_t)NPAD * 512 * 2;
  short* X2hi = (short*)w;  w += (size_t)NPAD * 512 * 2;
  short* X2lo = (short*)w;  w += (size_t)NPAD * 512 * 2;
  short* Bthi = (short*)w;  w += (size_t)512 * 512 * 2;
  short* Btlo = (short*)w;  w += (size_t)512 * 512 * 2;
  size_t need = (size_t)(w - (char*)d_ws);
  if (ws_size < need) return;

  dim3 blk(256);
  dim3 tGrid(16, 16);
  dim3 pGrid(8, 4);        // 512x512 MFMA gemm
  dim3 gemmGrid(33, 12);   // main diffusion gemm
  dim3 btGrid(8, 32);      // buildt: n-tiles x b
  dim3 wruGrid(32, 16, 2);
  dim3 wcGrid(32, 16);

  // --- precompute Chebyshev operator stack via MFMA ---
  k_prepT<<<1024, blk, 0, stream>>>(graph, Thi, Tlo, 512 * 512);
  t512<<<tGrid, blk, 0, stream>>>(graph, Bthi, Btlo);
  gemm_mfma_split<<<pGrid, blk, 0, stream>>>(Thi, Tlo, Bthi, Btlo, TMP, 512, 512);
  k_cheb2b<<<1024, blk, 0, stream>>>(TMP, Thi + 512 * 512, Tlo + 512 * 512);
  t512<<<tGrid, blk, 0, stream>>>(TMP, Bthi, Btlo);
  gemm_mfma_split<<<pGrid, blk, 0, stream>>>(Thi, Tlo, Bthi, Btlo, TMP, 512, 512);
  k_cheb3b<<<1024, blk, 0, stream>>>(TMP, graph, Thi + 1024 * 512, Tlo + 1024 * 512);
  k_zero<<<4096, blk, 0, stream>>>(Hbuf, 32 * 512 * 64);

  // --- encoder ---
  for (int t = 0; t < 12; ++t) {
    k_buildt<<<btGrid, blk, 0, stream>>>(Xthi, Xtlo, X2hi, X2lo, Hbuf, inputs, 0, t);
    gemm_mfma_split<<<gemmGrid, blk, 0, stream>>>(Thi, Tlo, Xthi, Xtlo, XS, NC, NC);
    k_wru<<<wruGrid, blk, 0, stream>>>(Xthi, Xtlo, XS, eWru, ebru, Hbuf, X2hi, X2lo, Ubuf);
    gemm_mfma_split<<<gemmGrid, blk, 0, stream>>>(Thi, Tlo, X2hi, X2lo, XS, NC, NC);
    k_wc<<<wcGrid, blk, 0, stream>>>(X2hi, X2lo, XS, eWc, ebc, Ubuf, Hbuf,
                                     nullptr, nullptr, nullptr, 0);
  }
  // --- decoder (autoregressive) ---
  for (int s = 0; s < 12; ++s) {
    if (s == 0) k_buildt<<<btGrid, blk, 0, stream>>>(Xthi, Xtlo, X2hi, X2lo, Hbuf, out, 1, 0);
    else        k_buildt<<<btGrid, blk, 0, stream>>>(Xthi, Xtlo, X2hi, X2lo, Hbuf, out, 0, s - 1);
    gemm_mfma_split<<<gemmGrid, blk, 0, stream>>>(Thi, Tlo, Xthi, Xtlo, XS, NC, NC);
    k_wru<<<wruGrid, blk, 0, stream>>>(Xthi, Xtlo, XS, dWru, dbru, Hbuf, X2hi, X2lo, Ubuf);
    gemm_mfma_split<<<gemmGrid, blk, 0, stream>>>(Thi, Tlo, X2hi, X2lo, XS, NC, NC);
    k_wc<<<wcGrid, blk, 0, stream>>>(X2hi, X2lo, XS, dWc, dbc, Ubuf, Hbuf,
                                     dWo, dbo, out, s);
  }
}

// Round 4
// 2217.707 us; speedup vs baseline: 5.2438x; 1.2977x over previous
//
#include <hip/hip_runtime.h>
#include <hip/hip_bf16.h>
#include <math.h>

#define CC 65
#define LDB 320     // XSmix row length in elements (k = m*72 + d, zero-padded)

typedef __attribute__((ext_vector_type(8))) short bf16x8;
typedef __attribute__((ext_vector_type(4))) float f32x4;

__device__ __forceinline__ float b2f(short s) {
  unsigned u = ((unsigned)(unsigned short)s) << 16;
  return __uint_as_float(u);
}
__device__ __forceinline__ short f2bh(float x) {
  __hip_bfloat16 h = __float2bfloat16(x);
  return *(short*)&h;
}
__device__ __forceinline__ void f2b2(float x, short& hi, short& lo) {
  hi = f2bh(x);
  lo = f2bh(x - b2f(hi));
}

#define GLOAD(src, dst) \
  __builtin_amdgcn_global_load_lds( \
      (const __attribute__((address_space(1))) void*)(src), \
      (__attribute__((address_space(3))) void*)(dst), 16, 0, 0)

// ---------------- utility kernels ----------------
__global__ void k_zero4(uint4* p, int n) {
  int i = blockIdx.x * 256 + threadIdx.x;
  if (i < n) p[i] = (uint4){0, 0, 0, 0};
}

// identity block of the T-stack (rows 0..511)
__global__ void k_ident(short* __restrict__ hi, short* __restrict__ lo) {
  int i = blockIdx.x * 256 + threadIdx.x;
  if (i >= 512 * 512) return;
  int r = i >> 9, c = i & 511;
  hi[i] = (r == c) ? (short)0x3F80 : (short)0;
  lo[i] = 0;
}

// split fp32 -> bf16 hi + lo
__global__ void k_prepT(const float* __restrict__ S, short* __restrict__ hi,
                        short* __restrict__ lo, int n) {
  int i = blockIdx.x * 256 + threadIdx.x;
  if (i >= n) return;
  short h, l; f2b2(S[i], h, l);
  hi[i] = h; lo[i] = l;
}

// T2 = 2*AA - I ; writes f32 back in place and split into hi/lo
__global__ void k_cheb2b(float* __restrict__ AA, short* __restrict__ hi,
                         short* __restrict__ lo) {
  int i = blockIdx.x * 256 + threadIdx.x;
  if (i >= 512 * 512) return;
  int r = i >> 9, c = i & 511;
  float v = 2.f * AA[i] - (r == c ? 1.f : 0.f);
  AA[i] = v;
  short h, l; f2b2(v, h, l);
  hi[i] = h; lo[i] = l;
}

// T3 = 2*(A@T2) - A ; split only
__global__ void k_cheb3b(const float* __restrict__ AT2, const float* __restrict__ A,
                         short* __restrict__ hi, short* __restrict__ lo) {
  int i = blockIdx.x * 256 + threadIdx.x;
  if (i >= 512 * 512) return;
  float v = 2.f * AT2[i] - A[i];
  short h, l; f2b2(v, h, l);
  hi[i] = h; lo[i] = l;
}

// transpose + split a 512x512 f32 matrix -> [c][r] bf16 hi/lo
__global__ __launch_bounds__(256) void t512(const float* __restrict__ in,
                                            short* __restrict__ ohi,
                                            short* __restrict__ olo) {
  __shared__ float t[32][33];
  int c0 = blockIdx.x * 32, r0 = blockIdx.y * 32;
  int tid = threadIdx.x;
  int cc = tid & 31, rr = tid >> 5;
#pragma unroll
  for (int p = 0; p < 4; ++p)
    t[rr + p * 8][cc] = in[(size_t)(r0 + rr + p * 8) * 512 + c0 + cc];
  __syncthreads();
#pragma unroll
  for (int p = 0; p < 4; ++p) {
    int c = rr + p * 8, r = cc;
    short h, l; f2b2(t[r][c], h, l);
    size_t o = (size_t)(c0 + c) * 512 + r0 + r;
    ohi[o] = h; olo[o] = l;
  }
}

// Wt[j][k = m*72+d] = W[(d*4+m)][j], zero-padded; split hi/lo. [J][320]
__global__ void k_prepW(const float* __restrict__ W, short* __restrict__ hi,
                        short* __restrict__ lo, int J) {
  int i = blockIdx.x * 256 + threadIdx.x;
  if (i >= J * LDB) return;
  int j = i / LDB, k = i - j * LDB;
  int m = k / 72, d = k - m * 72;
  float v = (m < 4 && d < 65) ? W[(size_t)(d * 4 + m) * J + j] : 0.f;
  short h, l; f2b2(v, h, l);
  hi[i] = h; lo[i] = l;
}

// write x(t=0) column into Xt and X2t
__global__ void k_setx0(const float* __restrict__ inp, short* __restrict__ Xthi,
                        short* __restrict__ Xtlo, short* __restrict__ X2hi,
                        short* __restrict__ X2lo) {
  int i = blockIdx.x * 256 + threadIdx.x;
  if (i >= 32 * 512) return;
  int b = i >> 9, n = i & 511;
  float x = inp[(size_t)b * 6144 + n];
  short h, l; f2b2(x, h, l);
  size_t o = ((size_t)b * CC) * 512 + n;
  Xthi[o] = h; Xtlo[o] = l; X2hi[o] = h; X2lo[o] = l;
}

// ---------------- generic single-pass split GEMM: C = (Ahi+Alo)(Bhi+Blo)^T ----
// A rows [*,512], B rows [*,512] (= C columns), BM=128 BN=64 BK=64, 4 waves.
// mode 0: C f32 row-major [ldc].  mode 1: transpose-split write into XSmix.
__global__ __launch_bounds__(256) void gemm_bt(
    const short* __restrict__ Ahi, const short* __restrict__ Alo,
    const short* __restrict__ Bhi, const short* __restrict__ Blo,
    float* __restrict__ Cf, int ldc,
    short* __restrict__ XShi, short* __restrict__ XSlo, int mode) {
  __shared__ short smem[24576];  // 48 KB: Ah|Al|Bh|Bl ; reused by epilogue
  short* Ah = smem;
  short* Al = Ah + 128 * 64;
  short* Bh = Al + 128 * 64;
  short* Bl = Bh + 64 * 64;
  int tid = threadIdx.x, lane = tid & 63, wid = tid >> 6;
  int r0 = blockIdx.y * 128, c0 = blockIdx.x * 64;
  int wr = wid >> 1, wc = wid & 1;

  f32x4 acc[4][2];
#pragma unroll
  for (int i = 0; i < 4; ++i)
#pragma unroll
    for (int j = 0; j < 2; ++j) acc[i][j] = (f32x4){0.f, 0.f, 0.f, 0.f};

  int aoff[4], boff[2];
#pragma unroll
  for (int q = 0; q < 4; ++q) {
    int r = (wid * 4 + q) * 8 + (lane >> 3);
    aoff[q] = (r0 + r) * 512 + (((lane & 7) ^ (r & 7)) * 8);
  }
#pragma unroll
  for (int q = 0; q < 2; ++q) {
    int r = (wid * 2 + q) * 8 + (lane >> 3);
    boff[q] = (c0 + r) * 512 + (((lane & 7) ^ (r & 7)) * 8);
  }

  for (int k0 = 0; k0 < 512; k0 += 64) {
#pragma unroll
    for (int q = 0; q < 4; ++q) GLOAD(Ahi + aoff[q] + k0, Ah + (wid * 4 + q) * 512);
#pragma unroll
    for (int q = 0; q < 4; ++q) GLOAD(Alo + aoff[q] + k0, Al + (wid * 4 + q) * 512);
#pragma unroll
    for (int q = 0; q < 2; ++q) GLOAD(Bhi + boff[q] + k0, Bh + (wid * 2 + q) * 512);
#pragma unroll
    for (int q = 0; q < 2; ++q) GLOAD(Blo + boff[q] + k0, Bl + (wid * 2 + q) * 512);
    __syncthreads();
#pragma unroll
    for (int ks = 0; ks < 2; ++ks) {
      bf16x8 ah[4], al[4], bh[2], bl[2];
#pragma unroll
      for (int fm = 0; fm < 4; ++fm) {
        int r = wr * 64 + fm * 16 + (lane & 15);
        int j = (ks * 4 + (lane >> 4)) ^ (r & 7);
        ah[fm] = *(const bf16x8*)&Ah[r * 64 + j * 8];
        al[fm] = *(const bf16x8*)&Al[r * 64 + j * 8];
      }
#pragma unroll
      for (int fn = 0; fn < 2; ++fn) {
        int r = wc * 32 + fn * 16 + (lane & 15);
        int j = (ks * 4 + (lane >> 4)) ^ (r & 7);
        bh[fn] = *(const bf16x8*)&Bh[r * 64 + j * 8];
        bl[fn] = *(const bf16x8*)&Bl[r * 64 + j * 8];
      }
#pragma unroll
      for (int fm = 0; fm < 4; ++fm)
#pragma unroll
        for (int fn = 0; fn < 2; ++fn) {
          acc[fm][fn] = __builtin_amdgcn_mfma_f32_16x16x32_bf16(ah[fm], bh[fn], acc[fm][fn], 0, 0, 0);
          acc[fm][fn] = __builtin_amdgcn_mfma_f32_16x16x32_bf16(al[fm], bh[fn], acc[fm][fn], 0, 0, 0);
          acc[fm][fn] = __builtin_amdgcn_mfma_f32_16x16x32_bf16(ah[fm], bl[fn], acc[fm][fn], 0, 0, 0);
        }
    }
    __syncthreads();
  }

  if (mode == 0) {
#pragma unroll
    for (int fm = 0; fm < 4; ++fm)
#pragma unroll
      for (int fn = 0; fn < 2; ++fn) {
        int row = r0 + wr * 64 + fm * 16 + (lane >> 4) * 4;
        int col = c0 + wc * 32 + fn * 16 + (lane & 15);
#pragma unroll
        for (int rr = 0; rr < 4; ++rr)
          Cf[(size_t)(row + rr) * ldc + col] = acc[fm][fn][rr];
      }
  } else {
    // transpose via LDS, then write XSmix[(b*512+n)*320 + m*72 + d] split hi/lo
    short* hiT = smem;            // [64 n][132 r]
    short* loT = smem + 64 * 132;
#pragma unroll
    for (int fm = 0; fm < 4; ++fm)
#pragma unroll
      for (int fn = 0; fn < 2; ++fn) {
        int nl = wc * 32 + fn * 16 + (lane & 15);
        int rbase = wr * 64 + fm * 16 + (lane >> 4) * 4;
#pragma unroll
        for (int rr = 0; rr < 4; ++rr) {
          short h, l; f2b2(acc[fm][fn][rr], h, l);
          hiT[nl * 132 + rbase + rr] = h;
          loT[nl * 132 + rbase + rr] = l;
        }
      }
    __syncthreads();
    int nl = tid & 63, bslot = tid >> 6;
    int b = r0 / CC + bslot;
    if (b < 32) {
      int rowlo = max(b * CC, r0), rowhi = min(b * CC + CC, r0 + 128);
      if (rowlo < rowhi) {
        int m = blockIdx.x >> 3, n0 = (blockIdx.x & 7) * 64;
        size_t dst = ((size_t)b * 512 + n0 + nl) * LDB + m * 72;
        int d0 = rowlo - b * CC, d1 = rowhi - b * CC;
        int d = d0;
        if (d & 1) {
          int rl = b * CC + d - r0;
          XShi[dst + d] = hiT[nl * 132 + rl];
          XSlo[dst + d] = loT[nl * 132 + rl];
          ++d;
        }
        for (; d + 1 < d1; d += 2) {
          int rl = b * CC + d - r0;
          unsigned h2 = (unsigned short)hiT[nl * 132 + rl] |
                        ((unsigned)(unsigned short)hiT[nl * 132 + rl + 1] << 16);
          unsigned l2 = (unsigned short)loT[nl * 132 + rl] |
                        ((unsigned)(unsigned short)loT[nl * 132 + rl + 1] << 16);
          *(unsigned*)(XShi + dst + d) = h2;
          *(unsigned*)(XSlo + dst + d) = l2;
        }
        if (d < d1) {
          int rl = b * CC + d - r0;
          XShi[dst + d] = hiT[nl * 132 + rl];
          XSlo[dst + d] = loT[nl * 132 + rl];
        }
      }
    }
  }
}

// ---------------- mix GEMM (ru): gate[j 128, n 64] per b; sigmoid epilogue ----
__global__ __launch_bounds__(256) void k_mix_ru(
    const short* __restrict__ Whi, const short* __restrict__ Wlo,   // [128,320]
    const short* __restrict__ XShi, const short* __restrict__ XSlo, // [16384,320]
    const float* __restrict__ bias,                                 // [128]
    const short* __restrict__ Xthi, const short* __restrict__ Xtlo, // h-old
    short* __restrict__ X2hi, short* __restrict__ X2lo,             // r*h out
    float* __restrict__ Ut) {                                       // u out
  __shared__ short Ah[128 * 64], Al[128 * 64], Bh[64 * 64], Bl[64 * 64];
  int tid = threadIdx.x, lane = tid & 63, wid = tid >> 6;
  int n0 = blockIdx.x * 64, b = blockIdx.y;
  int wr = wid >> 1, wc = wid & 1;

  f32x4 acc[4][2];
#pragma unroll
  for (int i = 0; i < 4; ++i)
#pragma unroll
    for (int j = 0; j < 2; ++j) acc[i][j] = (f32x4){0.f, 0.f, 0.f, 0.f};

  int aoff[4], boff[2];
#pragma unroll
  for (int q = 0; q < 4; ++q) {
    int r = (wid * 4 + q) * 8 + (lane >> 3);
    aoff[q] = r * LDB + (((lane & 7) ^ (r & 7)) * 8);
  }
#pragma unroll
  for (int q = 0; q < 2; ++q) {
    int r = (wid * 2 + q) * 8 + (lane >> 3);
    boff[q] = (b * 512 + n0 + r) * LDB + (((lane & 7) ^ (r & 7)) * 8);
  }

  for (int k0 = 0; k0 < 320; k0 += 64) {
#pragma unroll
    for (int q = 0; q < 4; ++q) GLOAD(Whi + aoff[q] + k0, Ah + (wid * 4 + q) * 512);
#pragma unroll
    for (int q = 0; q < 4; ++q) GLOAD(Wlo + aoff[q] + k0, Al + (wid * 4 + q) * 512);
#pragma unroll
    for (int q = 0; q < 2; ++q) GLOAD(XShi + boff[q] + k0, Bh + (wid * 2 + q) * 512);
#pragma unroll
    for (int q = 0; q < 2; ++q) GLOAD(XSlo + boff[q] + k0, Bl + (wid * 2 + q) * 512);
    __syncthreads();
#pragma unroll
    for (int ks = 0; ks < 2; ++ks) {
      bf16x8 ah[4], al[4], bh[2], bl[2];
#pragma unroll
      for (int fm = 0; fm < 4; ++fm) {
        int r = wr * 64 + fm * 16 + (lane & 15);
        int j = (ks * 4 + (lane >> 4)) ^ (r & 7);
        ah[fm] = *(const bf16x8*)&Ah[r * 64 + j * 8];
        al[fm] = *(const bf16x8*)&Al[r * 64 + j * 8];
      }
#pragma unroll
      for (int fn = 0; fn < 2; ++fn) {
        int r = wc * 32 + fn * 16 + (lane & 15);
        int j = (ks * 4 + (lane >> 4)) ^ (r & 7);
        bh[fn] = *(const bf16x8*)&Bh[r * 64 + j * 8];
        bl[fn] = *(const bf16x8*)&Bl[r * 64 + j * 8];
      }
#pragma unroll
      for (int fm = 0; fm < 4; ++fm)
#pragma unroll
        for (int fn = 0; fn < 2; ++fn) {
          acc[fm][fn] = __builtin_amdgcn_mfma_f32_16x16x32_bf16(ah[fm], bh[fn], acc[fm][fn], 0, 0, 0);
          acc[fm][fn] = __builtin_amdgcn_mfma_f32_16x16x32_bf16(al[fm], bh[fn], acc[fm][fn], 0, 0, 0);
          acc[fm][fn] = __builtin_amdgcn_mfma_f32_16x16x32_bf16(ah[fm], bl[fn], acc[fm][fn], 0, 0, 0);
        }
    }
    __syncthreads();
  }

  if (wr == 0) {  // r-half: write r*h into X2t h-columns
#pragma unroll
    for (int fm = 0; fm < 4; ++fm)
#pragma unroll
      for (int fn = 0; fn < 2; ++fn) {
        int ng = n0 + wc * 32 + fn * 16 + (lane & 15);
#pragma unroll
        for (int rr = 0; rr < 4; ++rr) {
          int j = fm * 16 + (lane >> 4) * 4 + rr;
          float rg = 1.f / (1.f + expf(-(acc[fm][fn][rr] + bias[j])));
          size_t hrow = ((size_t)(b * CC + 1 + j)) * 512 + ng;
          float h = b2f(Xthi[hrow]) + b2f(Xtlo[hrow]);
          short hh, ll; f2b2(rg * h, hh, ll);
          X2hi[hrow] = hh; X2lo[hrow] = ll;
        }
      }
  } else {  // u-half
#pragma unroll
    for (int fm = 0; fm < 4; ++fm)
#pragma unroll
      for (int fn = 0; fn < 2; ++fn) {
        int ng = n0 + wc * 32 + fn * 16 + (lane & 15);
#pragma unroll
        for (int rr = 0; rr < 4; ++rr) {
          int j = fm * 16 + (lane >> 4) * 4 + rr;
          float u = 1.f / (1.f + expf(-(acc[fm][fn][rr] + bias[64 + j])));
          Ut[((size_t)b * 64 + j) * 512 + ng] = u;
        }
      }
  }
}

// ---------------- mix GEMM (c): tanh + GRU update + optional decoder output ----
__global__ __launch_bounds__(256) void k_mix_c(
    const short* __restrict__ Whi, const short* __restrict__ Wlo,   // [64,320]
    const short* __restrict__ XShi, const short* __restrict__ XSlo,
    const float* __restrict__ bias,                                 // [64]
    const float* __restrict__ Ut,
    short* __restrict__ Xthi, short* __restrict__ Xtlo,             // h in/out
    short* __restrict__ X2hi, short* __restrict__ X2lo,             // x-col feedback
    int dmode, const float* __restrict__ xsrc,
    const float* __restrict__ Wo, const float* __restrict__ bo,
    float* __restrict__ dout, int step) {
  __shared__ short Ah[64 * 64], Al[64 * 64], Bh[64 * 64], Bl[64 * 64];
  __shared__ float hls[64][66];
  int tid = threadIdx.x, lane = tid & 63, wid = tid >> 6;
  int n0 = blockIdx.x * 64, b = blockIdx.y;
  int wr = wid >> 1, wc = wid & 1;

  f32x4 acc[2][2];
#pragma unroll
  for (int i = 0; i < 2; ++i)
#pragma unroll
    for (int j = 0; j < 2; ++j) acc[i][j] = (f32x4){0.f, 0.f, 0.f, 0.f};

  int aoff[2], boff[2];
#pragma unroll
  for (int q = 0; q < 2; ++q) {
    int r = (wid * 2 + q) * 8 + (lane >> 3);
    aoff[q] = r * LDB + (((lane & 7) ^ (r & 7)) * 8);
    boff[q] = (b * 512 + n0 + r) * LDB + (((lane & 7) ^ (r & 7)) * 8);
  }

  for (int k0 = 0; k0 < 320; k0 += 64) {
#pragma unroll
    for (int q = 0; q < 2; ++q) GLOAD(Whi + aoff[q] + k0, Ah + (wid * 2 + q) * 512);
#pragma unroll
    for (int q = 0; q < 2; ++q) GLOAD(Wlo + aoff[q] + k0, Al + (wid * 2 + q) * 512);
#pragma unroll
    for (int q = 0; q < 2; ++q) GLOAD(XShi + boff[q] + k0, Bh + (wid * 2 + q) * 512);
#pragma unroll
    for (int q = 0; q < 2; ++q) GLOAD(XSlo + boff[q] + k0, Bl + (wid * 2 + q) * 512);
    __syncthreads();
#pragma unroll
    for (int ks = 0; ks < 2; ++ks) {
      bf16x8 ah[2], al[2], bh[2], bl[2];
#pragma unroll
      for (int fm = 0; fm < 2; ++fm) {
        int r = wr * 32 + fm * 16 + (lane & 15);
        int j = (ks * 4 + (lane >> 4)) ^ (r & 7);
        ah[fm] = *(const bf16x8*)&Ah[r * 64 + j * 8];
        al[fm] = *(const bf16x8*)&Al[r * 64 + j * 8];
      }
#pragma unroll
      for (int fn = 0; fn < 2; ++fn) {
        int r = wc * 32 + fn * 16 + (lane & 15);
        int j = (ks * 4 + (lane >> 4)) ^ (r & 7);
        bh[fn] = *(const bf16x8*)&Bh[r * 64 + j * 8];
        bl[fn] = *(const bf16x8*)&Bl[r * 64 + j * 8];
      }
#pragma unroll
      for (int fm = 0; fm < 2; ++fm)
#pragma unroll
        for (int fn = 0; fn < 2; ++fn) {
          acc[fm][fn] = __builtin_amdgcn_mfma_f32_16x16x32_bf16(ah[fm], bh[fn], acc[fm][fn], 0, 0, 0);
          acc[fm][fn] = __builtin_amdgcn_mfma_f32_16x16x32_bf16(al[fm], bh[fn], acc[fm][fn], 0, 0, 0);
          acc[fm][fn] = __builtin_amdgcn_mfma_f32_16x16x32_bf16(ah[fm], bl[fn], acc[fm][fn], 0, 0, 0);
        }
    }
    __syncthreads();
  }

#pragma unroll
  for (int fm = 0; fm < 2; ++fm)
#pragma unroll
    for (int fn = 0; fn < 2; ++fn) {
      int nl = wc * 32 + fn * 16 + (lane & 15);
      int ng = n0 + nl;
#pragma unroll
      for (int rr = 0; rr < 4; ++rr) {
        int j = wr * 32 + fm * 16 + (lane >> 4) * 4 + rr;
        float cv = tanhf(acc[fm][fn][rr] + bias[j]);
        float u = Ut[((size_t)b * 64 + j) * 512 + ng];
        size_t hrow = ((size_t)(b * CC + 1 + j)) * 512 + ng;
        float h = b2f(Xthi[hrow]) + b2f(Xtlo[hrow]);
        float hn = u * h + (1.f - u) * cv;
        short hh, ll; f2b2(hn, hh, ll);
        Xthi[hrow] = hh; Xtlo[hrow] = ll;
        hls[j][nl] = hn;
      }
    }

  if (dmode) {
    __syncthreads();
    if (tid < 64) {
      int ng = n0 + tid;
      float s = bo[0];
#pragma unroll
      for (int j = 0; j < 64; ++j) s += hls[j][tid] * Wo[j];
      dout[((size_t)b * 12 + step) * 512 + ng] = s;
      short hh, ll; f2b2(s, hh, ll);
      size_t o = ((size_t)b * CC) * 512 + ng;
      Xthi[o] = hh; Xtlo[o] = ll; X2hi[o] = hh; X2lo[o] = ll;
    }
  } else {
    if (tid < 64) {
      int ng = n0 + tid;
      float x = xsrc ? xsrc[(size_t)b * 6144 + ng] : 0.f;
      short hh, ll; f2b2(x, hh, ll);
      size_t o = ((size_t)b * CC) * 512 + ng;
      Xthi[o] = hh; Xtlo[o] = ll; X2hi[o] = hh; X2lo[o] = ll;
    }
  }
}

extern "C" void kernel_launch(void* const* d_in, const int* in_sizes, int n_in,
                              void* d_out, int out_size, void* d_ws, size_t ws_size,
                              hipStream_t stream) {
  const float* inputs = (const float*)d_in[0];
  const float* graph  = (const float*)d_in[1];
  const float* eWru = (const float*)d_in[2];
  const float* ebru = (const float*)d_in[3];
  const float* eWc  = (const float*)d_in[4];
  const float* ebc  = (const float*)d_in[5];
  const float* dWru = (const float*)d_in[6];
  const float* dbru = (const float*)d_in[7];
  const float* dWc  = (const float*)d_in[8];
  const float* dbc  = (const float*)d_in[9];
  const float* dWo  = (const float*)d_in[10];
  const float* dbo  = (const float*)d_in[11];
  float* out = (float*)d_out;

  char* w = (char*)d_ws;
  auto carve = [&](size_t bytes) {
    char* p = w; w += (bytes + 255) & ~(size_t)255; return p;
  };
  short* Tshi = (short*)carve((size_t)2048 * 512 * 2);
  short* Tslo = (short*)carve((size_t)2048 * 512 * 2);
  short* Xthi = (short*)carve((size_t)2176 * 512 * 2);
  short* Xtlo = (short*)carve((size_t)2176 * 512 * 2);
  short* X2hi = (short*)carve((size_t)2176 * 512 * 2);
  short* X2lo = (short*)carve((size_t)2176 * 512 * 2);
  short* XShi = (short*)carve((size_t)16384 * LDB * 2);
  short* XSlo = (short*)carve((size_t)16384 * LDB * 2);
  float* Ut   = (float*)carve((size_t)2048 * 512 * 4);
  float* TMP  = (float*)carve((size_t)512 * 512 * 4);
  float* TMP2 = (float*)carve((size_t)512 * 512 * 4);
  short* Bthi = (short*)carve((size_t)512 * 512 * 2);
  short* Btlo = (short*)carve((size_t)512 * 512 * 2);
  short* eWruHi = (short*)carve((size_t)128 * LDB * 2);
  short* eWruLo = (short*)carve((size_t)128 * LDB * 2);
  short* eWcHi  = (short*)carve((size_t)64 * LDB * 2);
  short* eWcLo  = (short*)carve((size_t)64 * LDB * 2);
  short* dWruHi = (short*)carve((size_t)128 * LDB * 2);
  short* dWruLo = (short*)carve((size_t)128 * LDB * 2);
  short* dWcHi  = (short*)carve((size_t)64 * LDB * 2);
  short* dWcLo  = (short*)carve((size_t)64 * LDB * 2);
  if ((size_t)(w - (char*)d_ws) > ws_size) return;

  dim3 blk(256);
  // --- zero state buffers (pads must be clean every call) ---
  int nx4 = (int)((size_t)2176 * 512 * 2 / 16);
  k_zero4<<<(nx4 + 255) / 256, blk, 0, stream>>>((uint4*)Xthi, nx4);
  k_zero4<<<(nx4 + 255) / 256, blk, 0, stream>>>((uint4*)Xtlo, nx4);
  k_zero4<<<(nx4 + 255) / 256, blk, 0, stream>>>((uint4*)X2hi, nx4);
  k_zero4<<<(nx4 + 255) / 256, blk, 0, stream>>>((uint4*)X2lo, nx4);
  int ns4 = (int)((size_t)16384 * LDB * 2 / 16);
  k_zero4<<<(ns4 + 255) / 256, blk, 0, stream>>>((uint4*)XShi, ns4);
  k_zero4<<<(ns4 + 255) / 256, blk, 0, stream>>>((uint4*)XSlo, ns4);

  // --- T-stack: [I; T1; T2; T3], split bf16 ---
  k_ident<<<1024, blk, 0, stream>>>(Tshi, Tslo);
  k_prepT<<<1024, blk, 0, stream>>>(graph, Tshi + 512 * 512, Tslo + 512 * 512, 512 * 512);
  t512<<<dim3(16, 16), blk, 0, stream>>>(graph, Bthi, Btlo);
  gemm_bt<<<dim3(8, 4), blk, 0, stream>>>(Tshi + 512 * 512, Tslo + 512 * 512,
                                          Bthi, Btlo, TMP, 512, nullptr, nullptr, 0);
  k_cheb2b<<<1024, blk, 0, stream>>>(TMP, Tshi + 1024 * 512, Tslo + 1024 * 512);
  t512<<<dim3(16, 16), blk, 0, stream>>>(TMP, Bthi, Btlo);
  gemm_bt<<<dim3(8, 4), blk, 0, stream>>>(Tshi + 512 * 512, Tslo + 512 * 512,
                                          Bthi, Btlo, TMP2, 512, nullptr, nullptr, 0);
  k_cheb3b<<<1024, blk, 0, stream>>>(TMP2, graph, Tshi + 1536 * 512, Tslo + 1536 * 512);

  // --- weights transposed/split ---
  k_prepW<<<160, blk, 0, stream>>>(eWru, eWruHi, eWruLo, 128);
  k_prepW<<<80,  blk, 0, stream>>>(eWc,  eWcHi,  eWcLo,  64);
  k_prepW<<<160, blk, 0, stream>>>(dWru, dWruHi, dWruLo, 128);
  k_prepW<<<80,  blk, 0, stream>>>(dWc,  dWcHi,  dWcLo,  64);
  k_setx0<<<64, blk, 0, stream>>>(inputs, Xthi, Xtlo, X2hi, X2lo);

  dim3 dGrid(32, 17);   // diffuse: 2048 cols / 64  x  2176 rows / 128
  dim3 mGrid(8, 32);    // mix: n-tiles x b

  for (int t = 0; t < 24; ++t) {
    bool enc = t < 12;
    const short* wruh = enc ? eWruHi : dWruHi;
    const short* wrul = enc ? eWruLo : dWruLo;
    const short* wch  = enc ? eWcHi  : dWcHi;
    const short* wcl  = enc ? eWcLo  : dWcLo;
    const float* bru  = enc ? ebru : dbru;
    const float* bc   = enc ? ebc  : dbc;

    gemm_bt<<<dGrid, blk, 0, stream>>>(Xthi, Xtlo, Tshi, Tslo,
                                       nullptr, 0, XShi, XSlo, 1);
    k_mix_ru<<<mGrid, blk, 0, stream>>>(wruh, wrul, XShi, XSlo, bru,
                                        Xthi, Xtlo, X2hi, X2lo, Ut);
    gemm_bt<<<dGrid, blk, 0, stream>>>(X2hi, X2lo, Tshi, Tslo,
                                       nullptr, 0, XShi, XSlo, 1);
    if (enc) {
      const float* xs = (t < 11) ? inputs + (size_t)(t + 1) * 512 : nullptr;
      k_mix_c<<<mGrid, blk, 0, stream>>>(wch, wcl, XShi, XSlo, bc, Ut,
                                         Xthi, Xtlo, X2hi, X2lo,
                                         0, xs, nullptr, nullptr, nullptr, 0);
    } else {
      k_mix_c<<<mGrid, blk, 0, stream>>>(wch, wcl, XShi, XSlo, bc, Ut,
                                         Xthi, Xtlo, X2hi, X2lo,
                                         1, nullptr, dWo, dbo, out, t - 12);
    }
  }
}

// Round 5
// 1828.407 us; speedup vs baseline: 6.3603x; 1.2129x over previous
//
#include <hip/hip_runtime.h>
#include <hip/hip_bf16.h>
#include <math.h>

#define CC 65
#define LDB 320     // XSmix row length: k = m*64+d (0..255), x at 256+m, pad to 320

typedef __attribute__((ext_vector_type(8))) short bf16x8;
typedef __attribute__((ext_vector_type(4))) float f32x4;

__device__ __forceinline__ float b2f(short s) {
  unsigned u = ((unsigned)(unsigned short)s) << 16;
  return __uint_as_float(u);
}
__device__ __forceinline__ short f2bh(float x) {
  __hip_bfloat16 h = __float2bfloat16(x);
  return *(short*)&h;
}
__device__ __forceinline__ void f2b2(float x, short& hi, short& lo) {
  hi = f2bh(x);
  lo = f2bh(x - b2f(hi));
}

#define GLOAD(src, dst) \
  __builtin_amdgcn_global_load_lds( \
      (const __attribute__((address_space(1))) void*)(src), \
      (__attribute__((address_space(3))) void*)(dst), 16, 0, 0)

// ---------------- utility kernels ----------------
__global__ void k_zero4(uint4* p, int n) {
  int i = blockIdx.x * 256 + threadIdx.x;
  if (i < n) p[i] = (uint4){0, 0, 0, 0};
}

// identity block of the T-stack (rows 0..511)
__global__ void k_ident(short* __restrict__ hi, short* __restrict__ lo) {
  int i = blockIdx.x * 256 + threadIdx.x;
  if (i >= 512 * 512) return;
  int r = i >> 9, c = i & 511;
  hi[i] = (r == c) ? (short)0x3F80 : (short)0;
  lo[i] = 0;
}

// split fp32 -> bf16 hi + lo
__global__ void k_prepT(const float* __restrict__ S, short* __restrict__ hi,
                        short* __restrict__ lo, int n) {
  int i = blockIdx.x * 256 + threadIdx.x;
  if (i >= n) return;
  short h, l; f2b2(S[i], h, l);
  hi[i] = h; lo[i] = l;
}

// T2 = 2*AA - I ; writes f32 back in place and split into hi/lo
__global__ void k_cheb2b(float* __restrict__ AA, short* __restrict__ hi,
                         short* __restrict__ lo) {
  int i = blockIdx.x * 256 + threadIdx.x;
  if (i >= 512 * 512) return;
  int r = i >> 9, c = i & 511;
  float v = 2.f * AA[i] - (r == c ? 1.f : 0.f);
  AA[i] = v;
  short h, l; f2b2(v, h, l);
  hi[i] = h; lo[i] = l;
}

// T3 = 2*(A@T2) - A ; split only
__global__ void k_cheb3b(const float* __restrict__ AT2, const float* __restrict__ A,
                         short* __restrict__ hi, short* __restrict__ lo) {
  int i = blockIdx.x * 256 + threadIdx.x;
  if (i >= 512 * 512) return;
  float v = 2.f * AT2[i] - A[i];
  short h, l; f2b2(v, h, l);
  hi[i] = h; lo[i] = l;
}

// transpose + split a 512x512 f32 matrix -> [c][r] bf16 hi/lo
__global__ __launch_bounds__(256) void t512(const float* __restrict__ in,
                                            short* __restrict__ ohi,
                                            short* __restrict__ olo) {
  __shared__ float t[32][33];
  int c0 = blockIdx.x * 32, r0 = blockIdx.y * 32;
  int tid = threadIdx.x;
  int cc = tid & 31, rr = tid >> 5;
#pragma unroll
  for (int p = 0; p < 4; ++p)
    t[rr + p * 8][cc] = in[(size_t)(r0 + rr + p * 8) * 512 + c0 + cc];
  __syncthreads();
#pragma unroll
  for (int p = 0; p < 4; ++p) {
    int c = rr + p * 8, r = cc;
    short h, l; f2b2(t[r][c], h, l);
    size_t o = (size_t)(c0 + c) * 512 + r0 + r;
    ohi[o] = h; olo[o] = l;
  }
}

// Wt[j][k]: k<256 -> W[(1+ (k&63))*4 + (k>>6)][j]; k in 256..259 -> W[k-256][j]; else 0
__global__ void k_prepW(const float* __restrict__ W, short* __restrict__ hi,
                        short* __restrict__ lo, int J) {
  int i = blockIdx.x * 256 + threadIdx.x;
  if (i >= J * LDB) return;
  int j = i / LDB, k = i - j * LDB;
  float v = 0.f;
  if (k < 256) {
    int m = k >> 6, dh = k & 63;
    v = W[(size_t)((1 + dh) * 4 + m) * J + j];
  } else if (k < 260) {
    v = W[(size_t)(k - 256) * J + j];
  }
  short h, l; f2b2(v, h, l);
  hi[i] = h; lo[i] = l;
}

// write x(t=0) into Xt and X2t x-rows (row 2048+b)
__global__ void k_setx0(const float* __restrict__ inp, short* __restrict__ Xthi,
                        short* __restrict__ Xtlo, short* __restrict__ X2hi,
                        short* __restrict__ X2lo) {
  int i = blockIdx.x * 256 + threadIdx.x;
  if (i >= 32 * 512) return;
  int b = i >> 9, n = i & 511;
  float x = inp[(size_t)b * 6144 + n];
  short h, l; f2b2(x, h, l);
  size_t o = ((size_t)(2048 + b)) * 512 + n;
  Xthi[o] = h; Xtlo[o] = l; X2hi[o] = h; X2lo[o] = l;
}

// ---------------- generic single-pass split GEMM: C = (Ahi+Alo)(Bhi+Blo)^T ----
// A rows [*,512], B rows [*,512] (= C columns), BM=128 BN=64 BK=64, 4 waves.
// mode 0: C f32 row-major [ldc].
// mode 1: coalesced split write into XSmix (A-rows: b*64+d for h, 2048+b for x).
__global__ __launch_bounds__(256) void gemm_bt(
    const short* __restrict__ Ahi, const short* __restrict__ Alo,
    const short* __restrict__ Bhi, const short* __restrict__ Blo,
    float* __restrict__ Cf, int ldc,
    short* __restrict__ XShi, short* __restrict__ XSlo, int mode) {
  __shared__ short smem[24576];  // 48 KB: Ah|Al|Bh|Bl ; reused by epilogue
  short* Ah = smem;
  short* Al = Ah + 128 * 64;
  short* Bh = Al + 128 * 64;
  short* Bl = Bh + 64 * 64;
  int tid = threadIdx.x, lane = tid & 63, wid = tid >> 6;
  int r0 = blockIdx.y * 128, c0 = blockIdx.x * 64;
  int wr = wid >> 1, wc = wid & 1;

  f32x4 acc[4][2];
#pragma unroll
  for (int i = 0; i < 4; ++i)
#pragma unroll
    for (int j = 0; j < 2; ++j) acc[i][j] = (f32x4){0.f, 0.f, 0.f, 0.f};

  int aoff[4], boff[2];
#pragma unroll
  for (int q = 0; q < 4; ++q) {
    int r = (wid * 4 + q) * 8 + (lane >> 3);
    aoff[q] = (r0 + r) * 512 + (((lane & 7) ^ (r & 7)) * 8);
  }
#pragma unroll
  for (int q = 0; q < 2; ++q) {
    int r = (wid * 2 + q) * 8 + (lane >> 3);
    boff[q] = (c0 + r) * 512 + (((lane & 7) ^ (r & 7)) * 8);
  }

  for (int k0 = 0; k0 < 512; k0 += 64) {
#pragma unroll
    for (int q = 0; q < 4; ++q) GLOAD(Ahi + aoff[q] + k0, Ah + (wid * 4 + q) * 512);
#pragma unroll
    for (int q = 0; q < 4; ++q) GLOAD(Alo + aoff[q] + k0, Al + (wid * 4 + q) * 512);
#pragma unroll
    for (int q = 0; q < 2; ++q) GLOAD(Bhi + boff[q] + k0, Bh + (wid * 2 + q) * 512);
#pragma unroll
    for (int q = 0; q < 2; ++q) GLOAD(Blo + boff[q] + k0, Bl + (wid * 2 + q) * 512);
    __syncthreads();
#pragma unroll
    for (int ks = 0; ks < 2; ++ks) {
      bf16x8 ah[4], al[4], bh[2], bl[2];
#pragma unroll
      for (int fm = 0; fm < 4; ++fm) {
        int r = wr * 64 + fm * 16 + (lane & 15);
        int j = (ks * 4 + (lane >> 4)) ^ (r & 7);
        ah[fm] = *(const bf16x8*)&Ah[r * 64 + j * 8];
        al[fm] = *(const bf16x8*)&Al[r * 64 + j * 8];
      }
#pragma unroll
      for (int fn = 0; fn < 2; ++fn) {
        int r = wc * 32 + fn * 16 + (lane & 15);
        int j = (ks * 4 + (lane >> 4)) ^ (r & 7);
        bh[fn] = *(const bf16x8*)&Bh[r * 64 + j * 8];
        bl[fn] = *(const bf16x8*)&Bl[r * 64 + j * 8];
      }
#pragma unroll
      for (int fm = 0; fm < 4; ++fm)
#pragma unroll
        for (int fn = 0; fn < 2; ++fn) {
          acc[fm][fn] = __builtin_amdgcn_mfma_f32_16x16x32_bf16(ah[fm], bh[fn], acc[fm][fn], 0, 0, 0);
          acc[fm][fn] = __builtin_amdgcn_mfma_f32_16x16x32_bf16(al[fm], bh[fn], acc[fm][fn], 0, 0, 0);
          acc[fm][fn] = __builtin_amdgcn_mfma_f32_16x16x32_bf16(ah[fm], bl[fn], acc[fm][fn], 0, 0, 0);
        }
    }
    __syncthreads();
  }

  if (mode == 0) {
#pragma unroll
    for (int fm = 0; fm < 4; ++fm)
#pragma unroll
      for (int fn = 0; fn < 2; ++fn) {
        int row = r0 + wr * 64 + fm * 16 + (lane >> 4) * 4;
        int col = c0 + wc * 32 + fn * 16 + (lane & 15);
#pragma unroll
        for (int rr = 0; rr < 4; ++rr)
          Cf[(size_t)(row + rr) * ldc + col] = acc[fm][fn][rr];
      }
  } else {
    // pack hi|lo into u32, LDS-transpose, then coalesced 8-B global stores.
    unsigned* uT = (unsigned*)smem;  // [64 n][140 r] u32, stride 140 (16B-aligned, conflict-free)
#pragma unroll
    for (int fm = 0; fm < 4; ++fm)
#pragma unroll
      for (int fn = 0; fn < 2; ++fn) {
        int nl = wc * 32 + fn * 16 + (lane & 15);
        int rbase = wr * 64 + fm * 16 + (lane >> 4) * 4;
        unsigned pk[4];
#pragma unroll
        for (int rr = 0; rr < 4; ++rr) {
          short h, l; f2b2(acc[fm][fn][rr], h, l);
          pk[rr] = (unsigned)(unsigned short)h | ((unsigned)(unsigned short)l << 16);
        }
        uint2 w0; w0.x = pk[0]; w0.y = pk[1];
        uint2 w1; w1.x = pk[2]; w1.y = pk[3];
        *(uint2*)&uT[nl * 140 + rbase] = w0;
        *(uint2*)&uT[nl * 140 + rbase + 2] = w1;
      }
    __syncthreads();
    int m = blockIdx.x >> 3, n0s = (blockIdx.x & 7) * 64;
    if (r0 < 2048) {
      int b0 = r0 >> 6;  // two full b-spans per block
#pragma unroll
      for (int l = 0; l < 8; ++l) {
        int e = tid + l * 256;
        int ch = e & 15, bg = (e >> 4) & 1, nl = e >> 5;
        uint4 v = *(const uint4*)&uT[nl * 140 + bg * 64 + ch * 4];
        uint2 hi2, lo2;
        hi2.x = (v.x & 0xffffu) | (v.y << 16);
        hi2.y = (v.z & 0xffffu) | (v.w << 16);
        lo2.x = (v.x >> 16) | (v.y & 0xffff0000u);
        lo2.y = (v.z >> 16) | (v.w & 0xffff0000u);
        size_t dst = ((size_t)((b0 + bg) * 512 + n0s + nl)) * LDB + m * 64 + ch * 4;
        *(uint2*)(XShi + dst) = hi2;
        *(uint2*)(XSlo + dst) = lo2;
      }
    } else {
      // x block: local rows 0..31 = b
#pragma unroll
      for (int l = 0; l < 8; ++l) {
        int e = tid + l * 256;
        int nl = e & 63, b = e >> 6;
        unsigned v = uT[nl * 140 + b];
        size_t dst = ((size_t)(b * 512 + n0s + nl)) * LDB + 256 + m;
        XShi[dst] = (short)(v & 0xffffu);
        XSlo[dst] = (short)(v >> 16);
      }
    }
  }
}

// ---------------- mix GEMM (ru): gate[j 128, n 64] per b; sigmoid epilogue ----
__global__ __launch_bounds__(256) void k_mix_ru(
    const short* __restrict__ Whi, const short* __restrict__ Wlo,   // [128,320]
    const short* __restrict__ XShi, const short* __restrict__ XSlo, // [16384,320]
    const float* __restrict__ bias,                                 // [128]
    const short* __restrict__ Xthi, const short* __restrict__ Xtlo, // h-old
    short* __restrict__ X2hi, short* __restrict__ X2lo,             // r*h out
    float* __restrict__ Ut) {                                       // u out
  __shared__ short Ah[128 * 64], Al[128 * 64], Bh[64 * 64], Bl[64 * 64];
  int tid = threadIdx.x, lane = tid & 63, wid = tid >> 6;
  int n0 = blockIdx.x * 64, b = blockIdx.y;
  int wr = wid >> 1, wc = wid & 1;

  f32x4 acc[4][2];
#pragma unroll
  for (int i = 0; i < 4; ++i)
#pragma unroll
    for (int j = 0; j < 2; ++j) acc[i][j] = (f32x4){0.f, 0.f, 0.f, 0.f};

  int aoff[4], boff[2];
#pragma unroll
  for (int q = 0; q < 4; ++q) {
    int r = (wid * 4 + q) * 8 + (lane >> 3);
    aoff[q] = r * LDB + (((lane & 7) ^ (r & 7)) * 8);
  }
#pragma unroll
  for (int q = 0; q < 2; ++q) {
    int r = (wid * 2 + q) * 8 + (lane >> 3);
    boff[q] = (b * 512 + n0 + r) * LDB + (((lane & 7) ^ (r & 7)) * 8);
  }

  for (int k0 = 0; k0 < 320; k0 += 64) {
#pragma unroll
    for (int q = 0; q < 4; ++q) GLOAD(Whi + aoff[q] + k0, Ah + (wid * 4 + q) * 512);
#pragma unroll
    for (int q = 0; q < 4; ++q) GLOAD(Wlo + aoff[q] + k0, Al + (wid * 4 + q) * 512);
#pragma unroll
    for (int q = 0; q < 2; ++q) GLOAD(XShi + boff[q] + k0, Bh + (wid * 2 + q) * 512);
#pragma unroll
    for (int q = 0; q < 2; ++q) GLOAD(XSlo + boff[q] + k0, Bl + (wid * 2 + q) * 512);
    __syncthreads();
#pragma unroll
    for (int ks = 0; ks < 2; ++ks) {
      bf16x8 ah[4], al[4], bh[2], bl[2];
#pragma unroll
      for (int fm = 0; fm < 4; ++fm) {
        int r = wr * 64 + fm * 16 + (lane & 15);
        int j = (ks * 4 + (lane >> 4)) ^ (r & 7);
        ah[fm] = *(const bf16x8*)&Ah[r * 64 + j * 8];
        al[fm] = *(const bf16x8*)&Al[r * 64 + j * 8];
      }
#pragma unroll
      for (int fn = 0; fn < 2; ++fn) {
        int r = wc * 32 + fn * 16 + (lane & 15);
        int j = (ks * 4 + (lane >> 4)) ^ (r & 7);
        bh[fn] = *(const bf16x8*)&Bh[r * 64 + j * 8];
        bl[fn] = *(const bf16x8*)&Bl[r * 64 + j * 8];
      }
#pragma unroll
      for (int fm = 0; fm < 4; ++fm)
#pragma unroll
        for (int fn = 0; fn < 2; ++fn) {
          acc[fm][fn] = __builtin_amdgcn_mfma_f32_16x16x32_bf16(ah[fm], bh[fn], acc[fm][fn], 0, 0, 0);
          acc[fm][fn] = __builtin_amdgcn_mfma_f32_16x16x32_bf16(al[fm], bh[fn], acc[fm][fn], 0, 0, 0);
          acc[fm][fn] = __builtin_amdgcn_mfma_f32_16x16x32_bf16(ah[fm], bl[fn], acc[fm][fn], 0, 0, 0);
        }
    }
    __syncthreads();
  }

  if (wr == 0) {  // r-half: write r*h into X2t h-rows (b*64+j)
#pragma unroll
    for (int fm = 0; fm < 4; ++fm)
#pragma unroll
      for (int fn = 0; fn < 2; ++fn) {
        int ng = n0 + wc * 32 + fn * 16 + (lane & 15);
#pragma unroll
        for (int rr = 0; rr < 4; ++rr) {
          int j = fm * 16 + (lane >> 4) * 4 + rr;
          float rg = 1.f / (1.f + expf(-(acc[fm][fn][rr] + bias[j])));
          size_t hrow = ((size_t)(b * 64 + j)) * 512 + ng;
          float h = b2f(Xthi[hrow]) + b2f(Xtlo[hrow]);
          short hh, ll; f2b2(rg * h, hh, ll);
          X2hi[hrow] = hh; X2lo[hrow] = ll;
        }
      }
  } else {  // u-half
#pragma unroll
    for (int fm = 0; fm < 4; ++fm)
#pragma unroll
      for (int fn = 0; fn < 2; ++fn) {
        int ng = n0 + wc * 32 + fn * 16 + (lane & 15);
#pragma unroll
        for (int rr = 0; rr < 4; ++rr) {
          int j = fm * 16 + (lane >> 4) * 4 + rr;
          float u = 1.f / (1.f + expf(-(acc[fm][fn][rr] + bias[64 + j])));
          Ut[((size_t)b * 64 + j) * 512 + ng] = u;
        }
      }
  }
}

// ---------------- mix GEMM (c): tanh + GRU update + optional decoder output ----
__global__ __launch_bounds__(256) void k_mix_c(
    const short* __restrict__ Whi, const short* __restrict__ Wlo,   // [64,320]
    const short* __restrict__ XShi, const short* __restrict__ XSlo,
    const float* __restrict__ bias,                                 // [64]
    const float* __restrict__ Ut,
    short* __restrict__ Xthi, short* __restrict__ Xtlo,             // h in/out
    short* __restrict__ X2hi, short* __restrict__ X2lo,             // x-row feedback
    int dmode, const float* __restrict__ xsrc,
    const float* __restrict__ Wo, const float* __restrict__ bo,
    float* __restrict__ dout, int step) {
  __shared__ short Ah[64 * 64], Al[64 * 64], Bh[64 * 64], Bl[64 * 64];
  __shared__ float hls[64][66];
  int tid = threadIdx.x, lane = tid & 63, wid = tid >> 6;
  int n0 = blockIdx.x * 64, b = blockIdx.y;
  int wr = wid >> 1, wc = wid & 1;

  f32x4 acc[2][2];
#pragma unroll
  for (int i = 0; i < 2; ++i)
#pragma unroll
    for (int j = 0; j < 2; ++j) acc[i][j] = (f32x4){0.f, 0.f, 0.f, 0.f};

  int aoff[2], boff[2];
#pragma unroll
  for (int q = 0; q < 2; ++q) {
    int r = (wid * 2 + q) * 8 + (lane >> 3);
    aoff[q] = r * LDB + (((lane & 7) ^ (r & 7)) * 8);
    boff[q] = (b * 512 + n0 + r) * LDB + (((lane & 7) ^ (r & 7)) * 8);
  }

  for (int k0 = 0; k0 < 320; k0 += 64) {
#pragma unroll
    for (int q = 0; q < 2; ++q) GLOAD(Whi + aoff[q] + k0, Ah + (wid * 2 + q) * 512);
#pragma unroll
    for (int q = 0; q < 2; ++q) GLOAD(Wlo + aoff[q] + k0, Al + (wid * 2 + q) * 512);
#pragma unroll
    for (int q = 0; q < 2; ++q) GLOAD(XShi + boff[q] + k0, Bh + (wid * 2 + q) * 512);
#pragma unroll
    for (int q = 0; q < 2; ++q) GLOAD(XSlo + boff[q] + k0, Bl + (wid * 2 + q) * 512);
    __syncthreads();
#pragma unroll
    for (int ks = 0; ks < 2; ++ks) {
      bf16x8 ah[2], al[2], bh[2], bl[2];
#pragma unroll
      for (int fm = 0; fm < 2; ++fm) {
        int r = wr * 32 + fm * 16 + (lane & 15);
        int j = (ks * 4 + (lane >> 4)) ^ (r & 7);
        ah[fm] = *(const bf16x8*)&Ah[r * 64 + j * 8];
        al[fm] = *(const bf16x8*)&Al[r * 64 + j * 8];
      }
#pragma unroll
      for (int fn = 0; fn < 2; ++fn) {
        int r = wc * 32 + fn * 16 + (lane & 15);
        int j = (ks * 4 + (lane >> 4)) ^ (r & 7);
        bh[fn] = *(const bf16x8*)&Bh[r * 64 + j * 8];
        bl[fn] = *(const bf16x8*)&Bl[r * 64 + j * 8];
      }
#pragma unroll
      for (int fm = 0; fm < 2; ++fm)
#pragma unroll
        for (int fn = 0; fn < 2; ++fn) {
          acc[fm][fn] = __builtin_amdgcn_mfma_f32_16x16x32_bf16(ah[fm], bh[fn], acc[fm][fn], 0, 0, 0);
          acc[fm][fn] = __builtin_amdgcn_mfma_f32_16x16x32_bf16(al[fm], bh[fn], acc[fm][fn], 0, 0, 0);
          acc[fm][fn] = __builtin_amdgcn_mfma_f32_16x16x32_bf16(ah[fm], bl[fn], acc[fm][fn], 0, 0, 0);
        }
    }
    __syncthreads();
  }

#pragma unroll
  for (int fm = 0; fm < 2; ++fm)
#pragma unroll
    for (int fn = 0; fn < 2; ++fn) {
      int nl = wc * 32 + fn * 16 + (lane & 15);
      int ng = n0 + nl;
#pragma unroll
      for (int rr = 0; rr < 4; ++rr) {
        int j = wr * 32 + fm * 16 + (lane >> 4) * 4 + rr;
        float cv = tanhf(acc[fm][fn][rr] + bias[j]);
        float u = Ut[((size_t)b * 64 + j) * 512 + ng];
        size_t hrow = ((size_t)(b * 64 + j)) * 512 + ng;
        float h = b2f(Xthi[hrow]) + b2f(Xtlo[hrow]);
        float hn = u * h + (1.f - u) * cv;
        short hh, ll; f2b2(hn, hh, ll);
        Xthi[hrow] = hh; Xtlo[hrow] = ll;
        hls[j][nl] = hn;
      }
    }

  if (dmode) {
    __syncthreads();
    if (tid < 64) {
      int ng = n0 + tid;
      float s = bo[0];
#pragma unroll
      for (int j = 0; j < 64; ++j) s += hls[j][tid] * Wo[j];
      dout[((size_t)b * 12 + step) * 512 + ng] = s;
      short hh, ll; f2b2(s, hh, ll);
      size_t o = ((size_t)(2048 + b)) * 512 + ng;
      Xthi[o] = hh; Xtlo[o] = ll; X2hi[o] = hh; X2lo[o] = ll;
    }
  } else {
    if (tid < 64) {
      int ng = n0 + tid;
      float x = xsrc ? xsrc[(size_t)b * 6144 + ng] : 0.f;
      short hh, ll; f2b2(x, hh, ll);
      size_t o = ((size_t)(2048 + b)) * 512 + ng;
      Xthi[o] = hh; Xtlo[o] = ll; X2hi[o] = hh; X2lo[o] = ll;
    }
  }
}

extern "C" void kernel_launch(void* const* d_in, const int* in_sizes, int n_in,
                              void* d_out, int out_size, void* d_ws, size_t ws_size,
                              hipStream_t stream) {
  const float* inputs = (const float*)d_in[0];
  const float* graph  = (const float*)d_in[1];
  const float* eWru = (const float*)d_in[2];
  const float* ebru = (const float*)d_in[3];
  const float* eWc  = (const float*)d_in[4];
  const float* ebc  = (const float*)d_in[5];
  const float* dWru = (const float*)d_in[6];
  const float* dbru = (const float*)d_in[7];
  const float* dWc  = (const float*)d_in[8];
  const float* dbc  = (const float*)d_in[9];
  const float* dWo  = (const float*)d_in[10];
  const float* dbo  = (const float*)d_in[11];
  float* out = (float*)d_out;

  char* w = (char*)d_ws;
  auto carve = [&](size_t bytes) {
    char* p = w; w += (bytes + 255) & ~(size_t)255; return p;
  };
  short* Tshi = (short*)carve((size_t)2048 * 512 * 2);
  short* Tslo = (short*)carve((size_t)2048 * 512 * 2);
  short* Xthi = (short*)carve((size_t)2176 * 512 * 2);
  short* Xtlo = (short*)carve((size_t)2176 * 512 * 2);
  short* X2hi = (short*)carve((size_t)2176 * 512 * 2);
  short* X2lo = (short*)carve((size_t)2176 * 512 * 2);
  short* XShi = (short*)carve((size_t)16384 * LDB * 2);
  short* XSlo = (short*)carve((size_t)16384 * LDB * 2);
  float* Ut   = (float*)carve((size_t)2048 * 512 * 4);
  float* TMP  = (float*)carve((size_t)512 * 512 * 4);
  float* TMP2 = (float*)carve((size_t)512 * 512 * 4);
  short* Bthi = (short*)carve((size_t)512 * 512 * 2);
  short* Btlo = (short*)carve((size_t)512 * 512 * 2);
  short* eWruHi = (short*)carve((size_t)128 * LDB * 2);
  short* eWruLo = (short*)carve((size_t)128 * LDB * 2);
  short* eWcHi  = (short*)carve((size_t)64 * LDB * 2);
  short* eWcLo  = (short*)carve((size_t)64 * LDB * 2);
  short* dWruHi = (short*)carve((size_t)128 * LDB * 2);
  short* dWruLo = (short*)carve((size_t)128 * LDB * 2);
  short* dWcHi  = (short*)carve((size_t)64 * LDB * 2);
  short* dWcLo  = (short*)carve((size_t)64 * LDB * 2);
  if ((size_t)(w - (char*)d_ws) > ws_size) return;

  dim3 blk(256);
  // --- zero state buffers (pads + h0 must be clean every call) ---
  int nx4 = (int)((size_t)2176 * 512 * 2 / 16);
  k_zero4<<<(nx4 + 255) / 256, blk, 0, stream>>>((uint4*)Xthi, nx4);
  k_zero4<<<(nx4 + 255) / 256, blk, 0, stream>>>((uint4*)Xtlo, nx4);
  k_zero4<<<(nx4 + 255) / 256, blk, 0, stream>>>((uint4*)X2hi, nx4);
  k_zero4<<<(nx4 + 255) / 256, blk, 0, stream>>>((uint4*)X2lo, nx4);
  int ns4 = (int)((size_t)16384 * LDB * 2 / 16);
  k_zero4<<<(ns4 + 255) / 256, blk, 0, stream>>>((uint4*)XShi, ns4);
  k_zero4<<<(ns4 + 255) / 256, blk, 0, stream>>>((uint4*)XSlo, ns4);

  // --- T-stack: [I; T1; T2; T3], split bf16 ---
  k_ident<<<1024, blk, 0, stream>>>(Tshi, Tslo);
  k_prepT<<<1024, blk, 0, stream>>>(graph, Tshi + 512 * 512, Tslo + 512 * 512, 512 * 512);
  t512<<<dim3(16, 16), blk, 0, stream>>>(graph, Bthi, Btlo);
  gemm_bt<<<dim3(8, 4), blk, 0, stream>>>(Tshi + 512 * 512, Tslo + 512 * 512,
                                          Bthi, Btlo, TMP, 512, nullptr, nullptr, 0);
  k_cheb2b<<<1024, blk, 0, stream>>>(TMP, Tshi + 1024 * 512, Tslo + 1024 * 512);
  t512<<<dim3(16, 16), blk, 0, stream>>>(TMP, Bthi, Btlo);
  gemm_bt<<<dim3(8, 4), blk, 0, stream>>>(Tshi + 512 * 512, Tslo + 512 * 512,
                                          Bthi, Btlo, TMP2, 512, nullptr, nullptr, 0);
  k_cheb3b<<<1024, blk, 0, stream>>>(TMP2, graph, Tshi + 1536 * 512, Tslo + 1536 * 512);

  // --- weights transposed/split ---
  k_prepW<<<160, blk, 0, stream>>>(eWru, eWruHi, eWruLo, 128);
  k_prepW<<<80,  blk, 0, stream>>>(eWc,  eWcHi,  eWcLo,  64);
  k_prepW<<<160, blk, 0, stream>>>(dWru, dWruHi, dWruLo, 128);
  k_prepW<<<80,  blk, 0, stream>>>(dWc,  dWcHi,  dWcLo,  64);
  k_setx0<<<64, blk, 0, stream>>>(inputs, Xthi, Xtlo, X2hi, X2lo);

  dim3 dGrid(32, 17);   // diffuse: 2048 cols / 64  x  2176 rows / 128
  dim3 mGrid(8, 32);    // mix: n-tiles x b

  for (int t = 0; t < 24; ++t) {
    bool enc = t < 12;
    const short* wruh = enc ? eWruHi : dWruHi;
    const short* wrul = enc ? eWruLo : dWruLo;
    const short* wch  = enc ? eWcHi  : dWcHi;
    const short* wcl  = enc ? eWcLo  : dWcLo;
    const float* bru  = enc ? ebru : dbru;
    const float* bc   = enc ? ebc  : dbc;

    gemm_bt<<<dGrid, blk, 0, stream>>>(Xthi, Xtlo, Tshi, Tslo,
                                       nullptr, 0, XShi, XSlo, 1);
    k_mix_ru<<<mGrid, blk, 0, stream>>>(wruh, wrul, XShi, XSlo, bru,
                                        Xthi, Xtlo, X2hi, X2lo, Ut);
    gemm_bt<<<dGrid, blk, 0, stream>>>(X2hi, X2lo, Tshi, Tslo,
                                       nullptr, 0, XShi, XSlo, 1);
    if (enc) {
      const float* xs = (t < 11) ? inputs + (size_t)(t + 1) * 512 : nullptr;
      k_mix_c<<<mGrid, blk, 0, stream>>>(wch, wcl, XShi, XSlo, bc, Ut,
                                         Xthi, Xtlo, X2hi, X2lo,
                                         0, xs, nullptr, nullptr, nullptr, 0);
    } else {
      k_mix_c<<<mGrid, blk, 0, stream>>>(wch, wcl, XShi, XSlo, bc, Ut,
                                         Xthi, Xtlo, X2hi, X2lo,
                                         1, nullptr, dWo, dbo, out, t - 12);
    }
  }
}

// Round 6
// 1627.100 us; speedup vs baseline: 7.1472x; 1.1237x over previous
//
#include <hip/hip_runtime.h>
#include <hip/hip_bf16.h>
#include <math.h>

#define LDB 320   // XSmix row: k = m*64+dh (m=0 id, 1..3 = T_m), 256..259 = x,Tx; pad->320

typedef __attribute__((ext_vector_type(8))) short bf16x8;
typedef __attribute__((ext_vector_type(4))) float f32x4;

__device__ __forceinline__ float b2f(short s) {
  unsigned u = ((unsigned)(unsigned short)s) << 16;
  return __uint_as_float(u);
}
__device__ __forceinline__ short f2bh(float x) {
  __hip_bfloat16 h = __float2bfloat16(x);
  return *(short*)&h;
}
__device__ __forceinline__ void f2b2(float x, short& hi, short& lo) {
  hi = f2bh(x);
  lo = f2bh(x - b2f(hi));
}

#define GLOAD(src, dst) \
  __builtin_amdgcn_global_load_lds( \
      (const __attribute__((address_space(1))) void*)(src), \
      (__attribute__((address_space(3))) void*)(dst), 16, 0, 0)

// ---------------- utility kernels ----------------
__global__ void k_zero4(uint4* p, int n) {
  int i = blockIdx.x * 256 + threadIdx.x;
  if (i < n) p[i] = (uint4){0, 0, 0, 0};
}

__global__ void k_prepT(const float* __restrict__ S, short* __restrict__ hi,
                        short* __restrict__ lo, int n) {
  int i = blockIdx.x * 256 + threadIdx.x;
  if (i >= n) return;
  short h, l; f2b2(S[i], h, l);
  hi[i] = h; lo[i] = l;
}

__global__ void k_cheb2b(float* __restrict__ AA, short* __restrict__ hi,
                         short* __restrict__ lo) {
  int i = blockIdx.x * 256 + threadIdx.x;
  if (i >= 512 * 512) return;
  int r = i >> 9, c = i & 511;
  float v = 2.f * AA[i] - (r == c ? 1.f : 0.f);
  AA[i] = v;
  short h, l; f2b2(v, h, l);
  hi[i] = h; lo[i] = l;
}

__global__ void k_cheb3b(const float* __restrict__ AT2, const float* __restrict__ A,
                         short* __restrict__ hi, short* __restrict__ lo) {
  int i = blockIdx.x * 256 + threadIdx.x;
  if (i >= 512 * 512) return;
  float v = 2.f * AT2[i] - A[i];
  short h, l; f2b2(v, h, l);
  hi[i] = h; lo[i] = l;
}

// transpose + split a 512x512 f32 matrix -> [c][r] bf16 hi/lo
__global__ __launch_bounds__(256) void t512(const float* __restrict__ in,
                                            short* __restrict__ ohi,
                                            short* __restrict__ olo) {
  __shared__ float t[32][33];
  int c0 = blockIdx.x * 32, r0 = blockIdx.y * 32;
  int tid = threadIdx.x;
  int cc = tid & 31, rr = tid >> 5;
#pragma unroll
  for (int p = 0; p < 4; ++p)
    t[rr + p * 8][cc] = in[(size_t)(r0 + rr + p * 8) * 512 + c0 + cc];
  __syncthreads();
#pragma unroll
  for (int p = 0; p < 4; ++p) {
    int c = rr + p * 8, r = cc;
    short h, l; f2b2(t[r][c], h, l);
    size_t o = (size_t)(c0 + c) * 512 + r0 + r;
    ohi[o] = h; olo[o] = l;
  }
}

// Wt[j][k]: k<256 -> W[(1+(k&63))*4 + (k>>6)][j]; k 256..259 -> W[k-256][j]; else 0
__global__ void k_prepW(const float* __restrict__ W, short* __restrict__ hi,
                        short* __restrict__ lo, int J) {
  int i = blockIdx.x * 256 + threadIdx.x;
  if (i >= J * LDB) return;
  int j = i / LDB, k = i - j * LDB;
  float v = 0.f;
  if (k < 256) {
    int m = k >> 6, dh = k & 63;
    v = W[(size_t)((1 + dh) * 4 + m) * J + j];
  } else if (k < 260) {
    v = W[(size_t)(k - 256) * J + j];
  }
  short h, l; f2b2(v, h, l);
  hi[i] = h; lo[i] = l;
}

// x(t=0) -> Xt x-rows (2048+b) and XS k=256
__global__ void k_setx0(const float* __restrict__ inp, short* __restrict__ Xthi,
                        short* __restrict__ Xtlo, short* __restrict__ XShi,
                        short* __restrict__ XSlo) {
  int i = blockIdx.x * 256 + threadIdx.x;
  if (i >= 32 * 512) return;
  int b = i >> 9, n = i & 511;
  float x = inp[(size_t)b * 6144 + n];
  short h, l; f2b2(x, h, l);
  size_t o = ((size_t)(2048 + b)) * 512 + n;
  Xthi[o] = h; Xtlo[o] = l;
  size_t o2 = ((size_t)(b * 512 + n)) * LDB + 256;
  XShi[o2] = h; XSlo[o2] = l;
}

// ---------------- split GEMM, BM=128 BN=64 BK=32, 2-phase dbuf ----------------
// C = (Ahi+Alo) @ (Bhi+Blo)^T ; A rows [*,512], B rows [*,512].
// mode 0: C f32 [ldc].  mode 1: XSmix epilogue (h-rows m=1..3; x-block -> 257+mq).
__global__ __launch_bounds__(256) void gemm_bt(
    const short* __restrict__ Ahi, const short* __restrict__ Alo,
    const short* __restrict__ Bhi, const short* __restrict__ Blo,
    float* __restrict__ Cf, int ldc,
    short* __restrict__ XShi, short* __restrict__ XSlo, int mode) {
  __shared__ short smem[2 * 12288];  // per buf: Ah 4096 | Al 4096 | Bh 2048 | Bl 2048
  int tid = threadIdx.x, lane = tid & 63, wid = tid >> 6;
  int r0 = blockIdx.y * 128, c0 = blockIdx.x * 64;
  int wr = wid >> 1, wc = wid & 1;
  int l15 = lane & 15, l4 = lane >> 4;

  f32x4 acc[4][2];
#pragma unroll
  for (int i = 0; i < 4; ++i)
#pragma unroll
    for (int j = 0; j < 2; ++j) acc[i][j] = (f32x4){0.f, 0.f, 0.f, 0.f};

  int aoff[2];
#pragma unroll
  for (int q = 0; q < 2; ++q) {
    int r = (wid * 2 + q) * 16 + (lane >> 2);
    aoff[q] = (r0 + r) * 512 + (((lane & 3) ^ (r & 3)) * 8);
  }
  int rB = wid * 16 + (lane >> 2);
  int boff = (c0 + rB) * 512 + (((lane & 3) ^ (rB & 3)) * 8);

  int afr[4], bfr[2];
#pragma unroll
  for (int fm = 0; fm < 4; ++fm) {
    int ra = wr * 64 + fm * 16 + l15;
    afr[fm] = ra * 32 + ((l4 ^ (ra & 3)) * 8);
  }
#pragma unroll
  for (int fn = 0; fn < 2; ++fn) {
    int rb = wc * 32 + fn * 16 + l15;
    bfr[fn] = rb * 32 + ((l4 ^ (rb & 3)) * 8);
  }

#pragma unroll
  for (int q = 0; q < 2; ++q) {
    GLOAD(Ahi + aoff[q], smem + (wid * 2 + q) * 512);
    GLOAD(Alo + aoff[q], smem + 4096 + (wid * 2 + q) * 512);
  }
  GLOAD(Bhi + boff, smem + 8192 + wid * 512);
  GLOAD(Blo + boff, smem + 10240 + wid * 512);
  __syncthreads();

  int cur = 0;
#pragma unroll
  for (int t = 0; t < 16; ++t) {
    const short* cb = smem + cur * 12288;
    if (t < 15) {
      short* nb = smem + (cur ^ 1) * 12288;
      int k0 = (t + 1) * 32;
#pragma unroll
      for (int q = 0; q < 2; ++q) {
        GLOAD(Ahi + aoff[q] + k0, nb + (wid * 2 + q) * 512);
        GLOAD(Alo + aoff[q] + k0, nb + 4096 + (wid * 2 + q) * 512);
      }
      GLOAD(Bhi + boff + k0, nb + 8192 + wid * 512);
      GLOAD(Blo + boff + k0, nb + 10240 + wid * 512);
    }
    bf16x8 ah[4], al[4], bh[2], bl[2];
#pragma unroll
    for (int fm = 0; fm < 4; ++fm) {
      ah[fm] = *(const bf16x8*)&cb[afr[fm]];
      al[fm] = *(const bf16x8*)&cb[4096 + afr[fm]];
    }
#pragma unroll
    for (int fn = 0; fn < 2; ++fn) {
      bh[fn] = *(const bf16x8*)&cb[8192 + bfr[fn]];
      bl[fn] = *(const bf16x8*)&cb[10240 + bfr[fn]];
    }
#pragma unroll
    for (int fm = 0; fm < 4; ++fm)
#pragma unroll
      for (int fn = 0; fn < 2; ++fn) {
        acc[fm][fn] = __builtin_amdgcn_mfma_f32_16x16x32_bf16(ah[fm], bh[fn], acc[fm][fn], 0, 0, 0);
        acc[fm][fn] = __builtin_amdgcn_mfma_f32_16x16x32_bf16(al[fm], bh[fn], acc[fm][fn], 0, 0, 0);
        acc[fm][fn] = __builtin_amdgcn_mfma_f32_16x16x32_bf16(ah[fm], bl[fn], acc[fm][fn], 0, 0, 0);
      }
    __syncthreads();
    cur ^= 1;
  }

  if (mode == 0) {
#pragma unroll
    for (int fm = 0; fm < 4; ++fm)
#pragma unroll
      for (int fn = 0; fn < 2; ++fn) {
        int row = r0 + wr * 64 + fm * 16 + l4 * 4;
        int col = c0 + wc * 32 + fn * 16 + l15;
#pragma unroll
        for (int rr = 0; rr < 4; ++rr)
          Cf[(size_t)(row + rr) * ldc + col] = acc[fm][fn][rr];
      }
  } else {
    unsigned* uT = (unsigned*)smem;  // [64 n][140 r] packed hi|lo
#pragma unroll
    for (int fm = 0; fm < 4; ++fm)
#pragma unroll
      for (int fn = 0; fn < 2; ++fn) {
        int nl = wc * 32 + fn * 16 + l15;
        int rbase = wr * 64 + fm * 16 + l4 * 4;
        unsigned pk[4];
#pragma unroll
        for (int rr = 0; rr < 4; ++rr) {
          short h, l; f2b2(acc[fm][fn][rr], h, l);
          pk[rr] = (unsigned)(unsigned short)h | ((unsigned)(unsigned short)l << 16);
        }
        uint2 w0; w0.x = pk[0]; w0.y = pk[1];
        uint2 w1; w1.x = pk[2]; w1.y = pk[3];
        *(uint2*)&uT[nl * 140 + rbase] = w0;
        *(uint2*)&uT[nl * 140 + rbase + 2] = w1;
      }
    __syncthreads();
    int mq = blockIdx.x >> 3;        // 0..2 -> T_{mq+1}
    int n0s = (blockIdx.x & 7) * 64;
    if (r0 < 2048) {
      int b0 = r0 >> 6;
#pragma unroll
      for (int l = 0; l < 8; ++l) {
        int e = tid + l * 256;
        int ch = e & 15, bg = (e >> 4) & 1, nl = e >> 5;
        uint4 v = *(const uint4*)&uT[nl * 140 + bg * 64 + ch * 4];
        uint2 hi2, lo2;
        hi2.x = (v.x & 0xffffu) | (v.y << 16);
        hi2.y = (v.z & 0xffffu) | (v.w << 16);
        lo2.x = (v.x >> 16) | (v.y & 0xffff0000u);
        lo2.y = (v.z >> 16) | (v.w & 0xffff0000u);
        size_t dst = ((size_t)((b0 + bg) * 512 + n0s + nl)) * LDB + (mq + 1) * 64 + ch * 4;
        *(uint2*)(XShi + dst) = hi2;
        *(uint2*)(XSlo + dst) = lo2;
      }
    } else {
#pragma unroll
      for (int l = 0; l < 8; ++l) {
        int e = tid + l * 256;
        int nl = e & 63, b = e >> 6;
        unsigned v = uT[nl * 140 + b];
        size_t dst = ((size_t)(b * 512 + n0s + nl)) * LDB + 257 + mq;
        XShi[dst] = (short)(v & 0xffffu);
        XSlo[dst] = (short)(v >> 16);
      }
    }
  }
}

// ---------------- mix GEMM (ru): K=256 + f32 x-term; sigmoid epilogue ----------
__global__ __launch_bounds__(256) void k_mix_ru(
    const short* __restrict__ Whi, const short* __restrict__ Wlo,   // [128,320]
    short* __restrict__ XShi, short* __restrict__ XSlo,             // read + m0 write
    const float* __restrict__ bias,                                 // [128]
    const short* __restrict__ Xthi, const short* __restrict__ Xtlo, // h-old rows
    short* __restrict__ X2hi, short* __restrict__ X2lo,             // r*h rows
    float* __restrict__ Ut) {
  __shared__ short smem[2 * 12288];
  __shared__ float wx[128][4];
  __shared__ float xv[64][4];
  int tid = threadIdx.x, lane = tid & 63, wid = tid >> 6;
  int n0 = blockIdx.x * 64, b = blockIdx.y;
  int wr = wid >> 1, wc = wid & 1;
  int l15 = lane & 15, l4 = lane >> 4;

  if (tid < 128) {
#pragma unroll
    for (int m = 0; m < 4; ++m)
      wx[tid][m] = b2f(Whi[tid * LDB + 256 + m]) + b2f(Wlo[tid * LDB + 256 + m]);
  } else if (tid < 192) {
    int nl = tid - 128;
    size_t o = ((size_t)(b * 512 + n0 + nl)) * LDB + 256;
#pragma unroll
    for (int m = 0; m < 4; ++m)
      xv[nl][m] = b2f(XShi[o + m]) + b2f(XSlo[o + m]);
  }

  f32x4 acc[4][2];
#pragma unroll
  for (int i = 0; i < 4; ++i)
#pragma unroll
    for (int j = 0; j < 2; ++j) acc[i][j] = (f32x4){0.f, 0.f, 0.f, 0.f};

  int aoff[2];
#pragma unroll
  for (int q = 0; q < 2; ++q) {
    int r = (wid * 2 + q) * 16 + (lane >> 2);
    aoff[q] = r * LDB + (((lane & 3) ^ (r & 3)) * 8);
  }
  int rB = wid * 16 + (lane >> 2);
  size_t boff = ((size_t)(b * 512 + n0 + rB)) * LDB + (((lane & 3) ^ (rB & 3)) * 8);

  int afr[4], bfr[2];
#pragma unroll
  for (int fm = 0; fm < 4; ++fm) {
    int ra = wr * 64 + fm * 16 + l15;
    afr[fm] = ra * 32 + ((l4 ^ (ra & 3)) * 8);
  }
#pragma unroll
  for (int fn = 0; fn < 2; ++fn) {
    int rb = wc * 32 + fn * 16 + l15;
    bfr[fn] = rb * 32 + ((l4 ^ (rb & 3)) * 8);
  }

#pragma unroll
  for (int q = 0; q < 2; ++q) {
    GLOAD(Whi + aoff[q], smem + (wid * 2 + q) * 512);
    GLOAD(Wlo + aoff[q], smem + 4096 + (wid * 2 + q) * 512);
  }
  GLOAD(XShi + boff, smem + 8192 + wid * 512);
  GLOAD(XSlo + boff, smem + 10240 + wid * 512);
  __syncthreads();

  int cur = 0;
#pragma unroll
  for (int t = 0; t < 8; ++t) {
    const short* cb = smem + cur * 12288;
    if (t < 7) {
      short* nb = smem + (cur ^ 1) * 12288;
      int k0 = (t + 1) * 32;
#pragma unroll
      for (int q = 0; q < 2; ++q) {
        GLOAD(Whi + aoff[q] + k0, nb + (wid * 2 + q) * 512);
        GLOAD(Wlo + aoff[q] + k0, nb + 4096 + (wid * 2 + q) * 512);
      }
      GLOAD(XShi + boff + k0, nb + 8192 + wid * 512);
      GLOAD(XSlo + boff + k0, nb + 10240 + wid * 512);
    }
    bf16x8 ah[4], al[4], bh[2], bl[2];
#pragma unroll
    for (int fm = 0; fm < 4; ++fm) {
      ah[fm] = *(const bf16x8*)&cb[afr[fm]];
      al[fm] = *(const bf16x8*)&cb[4096 + afr[fm]];
    }
#pragma unroll
    for (int fn = 0; fn < 2; ++fn) {
      bh[fn] = *(const bf16x8*)&cb[8192 + bfr[fn]];
      bl[fn] = *(const bf16x8*)&cb[10240 + bfr[fn]];
    }
#pragma unroll
    for (int fm = 0; fm < 4; ++fm)
#pragma unroll
      for (int fn = 0; fn < 2; ++fn) {
        acc[fm][fn] = __builtin_amdgcn_mfma_f32_16x16x32_bf16(ah[fm], bh[fn], acc[fm][fn], 0, 0, 0);
        acc[fm][fn] = __builtin_amdgcn_mfma_f32_16x16x32_bf16(al[fm], bh[fn], acc[fm][fn], 0, 0, 0);
        acc[fm][fn] = __builtin_amdgcn_mfma_f32_16x16x32_bf16(ah[fm], bl[fn], acc[fm][fn], 0, 0, 0);
      }
    __syncthreads();
    cur ^= 1;
  }

#pragma unroll
  for (int fm = 0; fm < 4; ++fm)
#pragma unroll
    for (int fn = 0; fn < 2; ++fn) {
      int nl = wc * 32 + fn * 16 + l15;
      int ng = n0 + nl;
      int jb = wr * 64 + fm * 16 + l4 * 4;
      if (wr == 0) {
        short ph[4], pl[4];
#pragma unroll
        for (int rr = 0; rr < 4; ++rr) {
          int jg = jb + rr;
          float v = acc[fm][fn][rr] + wx[jg][0] * xv[nl][0] + wx[jg][1] * xv[nl][1]
                  + wx[jg][2] * xv[nl][2] + wx[jg][3] * xv[nl][3];
          float rg = 1.f / (1.f + expf(-(v + bias[jg])));
          size_t hrow = ((size_t)(b * 64 + jg)) * 512 + ng;
          float h = b2f(Xthi[hrow]) + b2f(Xtlo[hrow]);
          f2b2(rg * h, ph[rr], pl[rr]);
          X2hi[hrow] = ph[rr]; X2lo[hrow] = pl[rr];
        }
        size_t dst = ((size_t)(b * 512 + ng)) * LDB + jb;
        uint2 h2, l2;
        h2.x = (unsigned)(unsigned short)ph[0] | ((unsigned)(unsigned short)ph[1] << 16);
        h2.y = (unsigned)(unsigned short)ph[2] | ((unsigned)(unsigned short)ph[3] << 16);
        l2.x = (unsigned)(unsigned short)pl[0] | ((unsigned)(unsigned short)pl[1] << 16);
        l2.y = (unsigned)(unsigned short)pl[2] | ((unsigned)(unsigned short)pl[3] << 16);
        *(uint2*)(XShi + dst) = h2;
        *(uint2*)(XSlo + dst) = l2;
      } else {
#pragma unroll
        for (int rr = 0; rr < 4; ++rr) {
          int jg = jb + rr;  // 64..127
          float v = acc[fm][fn][rr] + wx[jg][0] * xv[nl][0] + wx[jg][1] * xv[nl][1]
                  + wx[jg][2] * xv[nl][2] + wx[jg][3] * xv[nl][3];
          float u = 1.f / (1.f + expf(-(v + bias[jg])));
          Ut[((size_t)(b * 64 + (jg - 64))) * 512 + ng] = u;
        }
      }
    }
}

// ---------------- mix GEMM (c): K=256 + x-term; tanh + GRU + decoder out -------
__global__ __launch_bounds__(256) void k_mix_c(
    const short* __restrict__ Whi, const short* __restrict__ Wlo,   // [64,320]
    short* __restrict__ XShi, short* __restrict__ XSlo,             // read + m0/x write
    const float* __restrict__ bias,                                 // [64]
    const float* __restrict__ Ut,
    short* __restrict__ Xthi, short* __restrict__ Xtlo,             // h rows + x rows
    int dmode, const float* __restrict__ xsrc,
    const float* __restrict__ Wo, const float* __restrict__ bo,
    float* __restrict__ dout, int step) {
  __shared__ short smem[2 * 8192];  // per buf: Ah 2048 | Al 2048 | Bh 2048 | Bl 2048
  __shared__ float wx[64][4];
  __shared__ float xv[64][4];
  __shared__ float hls[64][66];
  int tid = threadIdx.x, lane = tid & 63, wid = tid >> 6;
  int n0 = blockIdx.x * 64, b = blockIdx.y;
  int wr = wid >> 1, wc = wid & 1;
  int l15 = lane & 15, l4 = lane >> 4;

  if (tid < 64) {
#pragma unroll
    for (int m = 0; m < 4; ++m)
      wx[tid][m] = b2f(Whi[tid * LDB + 256 + m]) + b2f(Wlo[tid * LDB + 256 + m]);
  } else if (tid < 128) {
    int nl = tid - 64;
    size_t o = ((size_t)(b * 512 + n0 + nl)) * LDB + 256;
#pragma unroll
    for (int m = 0; m < 4; ++m)
      xv[nl][m] = b2f(XShi[o + m]) + b2f(XSlo[o + m]);
  }

  f32x4 acc[2][2];
#pragma unroll
  for (int i = 0; i < 2; ++i)
#pragma unroll
    for (int j = 0; j < 2; ++j) acc[i][j] = (f32x4){0.f, 0.f, 0.f, 0.f};

  int rA = wid * 16 + (lane >> 2);
  int aoff = rA * LDB + (((lane & 3) ^ (rA & 3)) * 8);
  size_t boff = ((size_t)(b * 512 + n0 + rA)) * LDB + (((lane & 3) ^ (rA & 3)) * 8);

  int afr[2], bfr[2];
#pragma unroll
  for (int fm = 0; fm < 2; ++fm) {
    int ra = wr * 32 + fm * 16 + l15;
    afr[fm] = ra * 32 + ((l4 ^ (ra & 3)) * 8);
  }
#pragma unroll
  for (int fn = 0; fn < 2; ++fn) {
    int rb = wc * 32 + fn * 16 + l15;
    bfr[fn] = rb * 32 + ((l4 ^ (rb & 3)) * 8);
  }

  GLOAD(Whi + aoff, smem + wid * 512);
  GLOAD(Wlo + aoff, smem + 2048 + wid * 512);
  GLOAD(XShi + boff, smem + 4096 + wid * 512);
  GLOAD(XSlo + boff, smem + 6144 + wid * 512);
  __syncthreads();

  int cur = 0;
#pragma unroll
  for (int t = 0; t < 8; ++t) {
    const short* cb = smem + cur * 8192;
    if (t < 7) {
      short* nb = smem + (cur ^ 1) * 8192;
      int k0 = (t + 1) * 32;
      GLOAD(Whi + aoff + k0, nb + wid * 512);
      GLOAD(Wlo + aoff + k0, nb + 2048 + wid * 512);
      GLOAD(XShi + boff + k0, nb + 4096 + wid * 512);
      GLOAD(XSlo + boff + k0, nb + 6144 + wid * 512);
    }
    bf16x8 ah[2], al[2], bh[2], bl[2];
#pragma unroll
    for (int fm = 0; fm < 2; ++fm) {
      ah[fm] = *(const bf16x8*)&cb[afr[fm]];
      al[fm] = *(const bf16x8*)&cb[2048 + afr[fm]];
    }
#pragma unroll
    for (int fn = 0; fn < 2; ++fn) {
      bh[fn] = *(const bf16x8*)&cb[4096 + bfr[fn]];
      bl[fn] = *(const bf16x8*)&cb[6144 + bfr[fn]];
    }
#pragma unroll
    for (int fm = 0; fm < 2; ++fm)
#pragma unroll
      for (int fn = 0; fn < 2; ++fn) {
        acc[fm][fn] = __builtin_amdgcn_mfma_f32_16x16x32_bf16(ah[fm], bh[fn], acc[fm][fn], 0, 0, 0);
        acc[fm][fn] = __builtin_amdgcn_mfma_f32_16x16x32_bf16(al[fm], bh[fn], acc[fm][fn], 0, 0, 0);
        acc[fm][fn] = __builtin_amdgcn_mfma_f32_16x16x32_bf16(ah[fm], bl[fn], acc[fm][fn], 0, 0, 0);
      }
    __syncthreads();
    cur ^= 1;
  }

#pragma unroll
  for (int fm = 0; fm < 2; ++fm)
#pragma unroll
    for (int fn = 0; fn < 2; ++fn) {
      int nl = wc * 32 + fn * 16 + l15;
      int ng = n0 + nl;
      int jb = wr * 32 + fm * 16 + l4 * 4;
      short ph[4], pl[4];
#pragma unroll
      for (int rr = 0; rr < 4; ++rr) {
        int jg = jb + rr;
        float v = acc[fm][fn][rr] + wx[jg][0] * xv[nl][0] + wx[jg][1] * xv[nl][1]
                + wx[jg][2] * xv[nl][2] + wx[jg][3] * xv[nl][3];
        float cv = tanhf(v + bias[jg]);
        size_t hrow = ((size_t)(b * 64 + jg)) * 512 + ng;
        float u = Ut[hrow];
        float h = b2f(Xthi[hrow]) + b2f(Xtlo[hrow]);
        float hn = u * h + (1.f - u) * cv;
        f2b2(hn, ph[rr], pl[rr]);
        Xthi[hrow] = ph[rr]; Xtlo[hrow] = pl[rr];
        hls[jg][nl] = hn;
      }
      size_t dst = ((size_t)(b * 512 + ng)) * LDB + jb;
      uint2 h2, l2;
      h2.x = (unsigned)(unsigned short)ph[0] | ((unsigned)(unsigned short)ph[1] << 16);
      h2.y = (unsigned)(unsigned short)ph[2] | ((unsigned)(unsigned short)ph[3] << 16);
      l2.x = (unsigned)(unsigned short)pl[0] | ((unsigned)(unsigned short)pl[1] << 16);
      l2.y = (unsigned)(unsigned short)pl[2] | ((unsigned)(unsigned short)pl[3] << 16);
      *(uint2*)(XShi + dst) = h2;
      *(uint2*)(XSlo + dst) = l2;
    }

  if (dmode) {
    __syncthreads();
    if (tid < 64) {
      int ng = n0 + tid;
      float s = bo[0];
#pragma unroll
      for (int j = 0; j < 64; ++j) s += hls[j][tid] * Wo[j];
      dout[((size_t)b * 12 + step) * 512 + ng] = s;
      short hh, ll; f2b2(s, hh, ll);
      size_t o = ((size_t)(2048 + b)) * 512 + ng;
      Xthi[o] = hh; Xtlo[o] = ll;
      size_t o2 = ((size_t)(b * 512 + ng)) * LDB + 256;
      XShi[o2] = hh; XSlo[o2] = ll;
    }
  } else {
    if (tid < 64) {
      int ng = n0 + tid;
      float x = xsrc ? xsrc[(size_t)b * 6144 + ng] : 0.f;
      short hh, ll; f2b2(x, hh, ll);
      size_t o = ((size_t)(2048 + b)) * 512 + ng;
      Xthi[o] = hh; Xtlo[o] = ll;
      size_t o2 = ((size_t)(b * 512 + ng)) * LDB + 256;
      XShi[o2] = hh; XSlo[o2] = ll;
    }
  }
}

extern "C" void kernel_launch(void* const* d_in, const int* in_sizes, int n_in,
                              void* d_out, int out_size, void* d_ws, size_t ws_size,
                              hipStream_t stream) {
  const float* inputs = (const float*)d_in[0];
  const float* graph  = (const float*)d_in[1];
  const float* eWru = (const float*)d_in[2];
  const float* ebru = (const float*)d_in[3];
  const float* eWc  = (const float*)d_in[4];
  const float* ebc  = (const float*)d_in[5];
  const float* dWru = (const float*)d_in[6];
  const float* dbru = (const float*)d_in[7];
  const float* dWc  = (const float*)d_in[8];
  const float* dbc  = (const float*)d_in[9];
  const float* dWo  = (const float*)d_in[10];
  const float* dbo  = (const float*)d_in[11];
  float* out = (float*)d_out;

  char* w = (char*)d_ws;
  auto carve = [&](size_t bytes) {
    char* p = w; w += (bytes + 255) & ~(size_t)255; return p;
  };
  short* Tshi = (short*)carve((size_t)1536 * 512 * 2);
  short* Tslo = (short*)carve((size_t)1536 * 512 * 2);
  short* Xthi = (short*)carve((size_t)2176 * 512 * 2);
  short* Xtlo = (short*)carve((size_t)2176 * 512 * 2);
  short* X2hi = (short*)carve((size_t)2048 * 512 * 2);
  short* X2lo = (short*)carve((size_t)2048 * 512 * 2);
  short* XShi = (short*)carve((size_t)16384 * LDB * 2);
  short* XSlo = (short*)carve((size_t)16384 * LDB * 2);
  float* Ut   = (float*)carve((size_t)2048 * 512 * 4);
  float* TMP  = (float*)carve((size_t)512 * 512 * 4);
  float* TMP2 = (float*)carve((size_t)512 * 512 * 4);
  short* Bthi = (short*)carve((size_t)512 * 512 * 2);
  short* Btlo = (short*)carve((size_t)512 * 512 * 2);
  short* eWruHi = (short*)carve((size_t)128 * LDB * 2);
  short* eWruLo = (short*)carve((size_t)128 * LDB * 2);
  short* eWcHi  = (short*)carve((size_t)64 * LDB * 2);
  short* eWcLo  = (short*)carve((size_t)64 * LDB * 2);
  short* dWruHi = (short*)carve((size_t)128 * LDB * 2);
  short* dWruLo = (short*)carve((size_t)128 * LDB * 2);
  short* dWcHi  = (short*)carve((size_t)64 * LDB * 2);
  short* dWcLo  = (short*)carve((size_t)64 * LDB * 2);
  if ((size_t)(w - (char*)d_ws) > ws_size) return;

  dim3 blk(256);
  // zero Xt (h0 + pads) and XS (m0 slots = h0)
  int nx4 = (int)((size_t)2176 * 512 * 2 / 16);
  k_zero4<<<(nx4 + 255) / 256, blk, 0, stream>>>((uint4*)Xthi, nx4);
  k_zero4<<<(nx4 + 255) / 256, blk, 0, stream>>>((uint4*)Xtlo, nx4);
  int ns4 = (int)((size_t)16384 * LDB * 2 / 16);
  k_zero4<<<(ns4 + 255) / 256, blk, 0, stream>>>((uint4*)XShi, ns4);
  k_zero4<<<(ns4 + 255) / 256, blk, 0, stream>>>((uint4*)XSlo, ns4);

  // T-stack [T1;T2;T3]
  k_prepT<<<1024, blk, 0, stream>>>(graph, Tshi, Tslo, 512 * 512);
  t512<<<dim3(16, 16), blk, 0, stream>>>(graph, Bthi, Btlo);
  gemm_bt<<<dim3(8, 4), blk, 0, stream>>>(Tshi, Tslo, Bthi, Btlo, TMP, 512,
                                          nullptr, nullptr, 0);
  k_cheb2b<<<1024, blk, 0, stream>>>(TMP, Tshi + 512 * 512, Tslo + 512 * 512);
  t512<<<dim3(16, 16), blk, 0, stream>>>(TMP, Bthi, Btlo);
  gemm_bt<<<dim3(8, 4), blk, 0, stream>>>(Tshi, Tslo, Bthi, Btlo, TMP2, 512,
                                          nullptr, nullptr, 0);
  k_cheb3b<<<1024, blk, 0, stream>>>(TMP2, graph, Tshi + 1024 * 512, Tslo + 1024 * 512);

  k_prepW<<<160, blk, 0, stream>>>(eWru, eWruHi, eWruLo, 128);
  k_prepW<<<80,  blk, 0, stream>>>(eWc,  eWcHi,  eWcLo,  64);
  k_prepW<<<160, blk, 0, stream>>>(dWru, dWruHi, dWruLo, 128);
  k_prepW<<<80,  blk, 0, stream>>>(dWc,  dWcHi,  dWcLo,  64);
  k_setx0<<<64, blk, 0, stream>>>(inputs, Xthi, Xtlo, XShi, XSlo);

  dim3 d1Grid(24, 17);  // h-rows + x-block
  dim3 d2Grid(24, 16);  // h-rows only (T*x slots persist)
  dim3 mGrid(8, 32);

  for (int t = 0; t < 24; ++t) {
    bool enc = t < 12;
    const short* wruh = enc ? eWruHi : dWruHi;
    const short* wrul = enc ? eWruLo : dWruLo;
    const short* wch  = enc ? eWcHi  : dWcHi;
    const short* wcl  = enc ? eWcLo  : dWcLo;
    const float* bru  = enc ? ebru : dbru;
    const float* bc   = enc ? ebc  : dbc;

    gemm_bt<<<d1Grid, blk, 0, stream>>>(Xthi, Xtlo, Tshi, Tslo,
                                        nullptr, 0, XShi, XSlo, 1);
    k_mix_ru<<<mGrid, blk, 0, stream>>>(wruh, wrul, XShi, XSlo, bru,
                                        Xthi, Xtlo, X2hi, X2lo, Ut);
    gemm_bt<<<d2Grid, blk, 0, stream>>>(X2hi, X2lo, Tshi, Tslo,
                                        nullptr, 0, XShi, XSlo, 1);
    if (enc) {
      const float* xs = (t < 11) ? inputs + (size_t)(t + 1) * 512 : nullptr;
      k_mix_c<<<mGrid, blk, 0, stream>>>(wch, wcl, XShi, XSlo, bc, Ut,
                                         Xthi, Xtlo, 0, xs,
                                         nullptr, nullptr, nullptr, 0);
    } else {
      k_mix_c<<<mGrid, blk, 0, stream>>>(wch, wcl, XShi, XSlo, bc, Ut,
                                         Xthi, Xtlo, 1, nullptr,
                                         dWo, dbo, out, t - 12);
    }
  }
}